// Round 6
// baseline (609.535 us; speedup 1.0000x reference)
//
#include <hip/hip_runtime.h>

// BondAwareEGNN fused layer — round 11.
//
// Round-10 post-mortem: spill gone (WRITE 125MB) but occ 83->66% and dur
// 218->230: occupancy vs per-wave state is a hard trade at ~56-64 regs.
// Root cause: every wave re-reads its whole W slice from L2 (3.8 GB/dispatch,
// 200cy dependent latency on all 64 MFMAs) for only 16 output rows.
//
// Round-11: persistent-weight GEMM for msg. Wave = one 16-col output tile,
// W fragments held IN REGISTERS for the whole kernel (W1 8 frags + W2 4 +
// Wc1 4 = 64 VGPR). Block = 8 waves (512thr) = 128 cols; 512 blocks
// grid-stride over 30000 16-row tiles (~59 tiles/block) -> W read from L2
// once per block (60x less W traffic). acc = single f32x4 (4 AGPR).
// Bias/w1c/wc2 are 5 per-lane scalar regs (col fixed per lane). 4 barriers
// per tile; T LDS = 4KB; next-tile bond metadata double-buffered, computed
// inside the layer-2 phase. __launch_bounds__(512,4) -> 2 blocks/CU.
// Spill detector: WRITE_SIZE must stay ~126MB. Node unchanged.

#define H      128
#define NA     20000
#define NB     60000
#define NBATCH 8
#define ADJ_CAP 32
#define NT_TILES (NB * NBATCH / 16)   // 30000
#define MSG_GRID 512

typedef __bf16 bf16;
typedef __bf16 bf16x4 __attribute__((ext_vector_type(4)));
typedef __bf16 bf16x8 __attribute__((ext_vector_type(8)));
typedef float  f32x4  __attribute__((ext_vector_type(4)));

__device__ __forceinline__ float silu_f(float v) {
  float e = __expf(-v);
  return v * __builtin_amdgcn_rcpf(1.0f + e);  // 1-ulp rcp; inf -> 0 ok
}

// XOR-swizzled index into a [R][128] bf16 tile. Row stride 256B (bank
// neutral); 16B chunk index XOR'd with row&7 rotates banks. Bijective per
// row; 8-element chunks stay contiguous so bf16x8 loads/stores still work.
__device__ __forceinline__ int tswz(int row, int col) {
  return (row << 7) + (((((col) >> 3) ^ (row & 7)) << 3) | (col & 7));
}

__global__ void cast_h(const float* __restrict__ src, bf16* __restrict__ dst) {
  int i = blockIdx.x * 256 + threadIdx.x;  // one float4 per thread
  float4 v = *(const float4*)(src + (size_t)i * 4);
  bf16x4 t = {(bf16)v.x, (bf16)v.y, (bf16)v.z, (bf16)v.w};
  *(bf16x4*)(dst + (size_t)i * 4) = t;
}

// fp32 KxN(128) row-major -> bf16 fragment-linear (8 bf16 per lane-frag).
__global__ void pack_w(const float* __restrict__ src, bf16* __restrict__ dst,
                       int K) {
  int i = blockIdx.x * 256 + threadIdx.x;
  if (i >= K * 128) return;
  int k = i >> 7, n = i & 127;
  int nt = n >> 4, ks = k >> 5;
  int lane = (((k >> 3) & 3) << 4) | (n & 15);
  int j = k & 7;
  int KS = K >> 5;
  dst[((((nt * KS + ks) * 64) + lane) << 3) + j] = (bf16)src[i];
}

// ---------------- adjacency build (fixed-capacity slots) ----------------
// degI doubles as the slot cursor; max deg for this input << ADJ_CAP.
__global__ void build_adj2(const int* __restrict__ bonds,
                           int* __restrict__ degI, int* __restrict__ adj2) {
  int e = blockIdx.x * 256 + threadIdx.x;
  if (e >= NB) return;
  int s = bonds[2 * e], d = bonds[2 * e + 1];
  int p = atomicAdd(&degI[s], 1);
  if (p < ADJ_CAP) adj2[s * ADJ_CAP + p] = (e << 1);        // src: sign -
  p = atomicAdd(&degI[d], 1);
  if (p < ADJ_CAP) adj2[d * ADJ_CAP + p] = (e << 1) | 1;    // dst: sign +
}

// ---------------- message kernel (persistent-W register GEMM) ----------------
__global__ __launch_bounds__(512, 4) void msg_kernel(
    const bf16* __restrict__ hb, const float* __restrict__ x,
    const int* __restrict__ bonds,
    const bf16* __restrict__ W1p, const float* __restrict__ bm1,
    const bf16* __restrict__ W2p, const float* __restrict__ bm2,
    const float* __restrict__ w1c,   // Wm1 row 256 (dist row), fp32[128]
    const bf16* __restrict__ Wc1p, const float* __restrict__ bc1,
    const float* __restrict__ Wc2,
    bf16* __restrict__ msgOut, float* __restrict__ updv) {
  __shared__ __align__(16) bf16 T[16 * 128];   // T, then messages (aliased)
  __shared__ float cds[2][16 * 3];
  __shared__ float dists[2][16];
  __shared__ float cwpart[8][16];

  const int tid = threadIdx.x;
  const int lane = tid & 63, w = tid >> 6;       // wave = 16-col tile owner
  const int quad = lane >> 4, l16 = lane & 15;
  const int colW = w * 16 + l16;

  // ---- persistent weight fragments (loaded once per block) ----
  const bf16x8* W1v  = (const bf16x8*)W1p;
  const bf16x8* W2v  = (const bf16x8*)W2p;
  const bf16x8* Wc1v = (const bf16x8*)Wc1p;
  bf16x8 w1f[8], w2f[4], wc1f[4];
#pragma unroll
  for (int ks = 0; ks < 8; ks++) w1f[ks] = W1v[(w * 8 + ks) * 64 + lane];
#pragma unroll
  for (int ks = 0; ks < 4; ks++) w2f[ks] = W2v[(w * 4 + ks) * 64 + lane];
#pragma unroll
  for (int ks = 0; ks < 4; ks++) wc1f[ks] = Wc1v[(w * 4 + ks) * 64 + lane];
  const float bm1c = bm1[colW], w1cc = w1c[colW], bm2c = bm2[colW];
  const float bc1c = bc1[colW], wc2c = Wc2[colW];

  int buf = 0;
  if (tid < 16) {                 // prologue: first tile's bond metadata
    int Rg = blockIdx.x * 16 + tid;
    int bond = Rg >> 3, bt = Rg & 7;
    int s = bonds[2 * bond], dn = bonds[2 * bond + 1];
    const float* xs = x + (size_t)(bt * NA + s) * 3;
    const float* xd = x + (size_t)(bt * NA + dn) * 3;
    float c0 = xd[0] - xs[0], c1 = xd[1] - xs[1], c2 = xd[2] - xs[2];
    cds[0][tid * 3 + 0] = c0; cds[0][tid * 3 + 1] = c1;
    cds[0][tid * 3 + 2] = c2;
    dists[0][tid] = sqrtf(c0 * c0 + c1 * c1 + c2 * c2);
  }
  __syncthreads();

  for (int t = blockIdx.x; t < NT_TILES; t += MSG_GRID) {
    // ---- layer 1: A gather (only steady-state memory traffic) ----
    const int Rg = t * 16 + l16;
    const int bond = Rg >> 3, bat = Rg & 7;
    const int sA = bonds[2 * bond], dA = bonds[2 * bond + 1];
    const bf16* hs = hb + (size_t)(bat * NA + sA) * H;
    const bf16* hd = hb + (size_t)(bat * NA + dA) * H;
    bf16x8 a[8];
#pragma unroll
    for (int ks = 0; ks < 4; ks++)
      a[ks] = *(const bf16x8*)(hs + ks * 32 + quad * 8);
#pragma unroll
    for (int ks = 0; ks < 4; ks++)
      a[4 + ks] = *(const bf16x8*)(hd + ks * 32 + quad * 8);

    f32x4 acc = (f32x4){0.f, 0.f, 0.f, 0.f};
#pragma unroll
    for (int ks = 0; ks < 8; ks++)
      acc = __builtin_amdgcn_mfma_f32_16x16x32_bf16(a[ks], w1f[ks], acc, 0, 0, 0);
#pragma unroll
    for (int reg = 0; reg < 4; reg++) {
      int row = quad * 4 + reg;
      float v = acc[reg] + bm1c + dists[buf][row] * w1cc;
      T[tswz(row, colW)] = (bf16)silu_f(v);
    }
    __syncthreads();   // (A) T ready

    // ---- layer 2 ----
    f32x4 acc2 = (f32x4){0.f, 0.f, 0.f, 0.f};
#pragma unroll
    for (int ks = 0; ks < 4; ks++) {
      bf16x8 aa = *(const bf16x8*)&T[tswz(l16, ks * 32 + quad * 8)];
      acc2 = __builtin_amdgcn_mfma_f32_16x16x32_bf16(aa, w2f[ks], acc2, 0, 0, 0);
    }
    // pipelined: next tile's bond metadata into the other buffer
    if (tid < 16) {
      int tn = t + MSG_GRID;
      if (tn < NT_TILES) {
        int Rg2 = tn * 16 + tid;
        int bond2 = Rg2 >> 3, bt2 = Rg2 & 7;
        int s2 = bonds[2 * bond2], dn2 = bonds[2 * bond2 + 1];
        const float* xs = x + (size_t)(bt2 * NA + s2) * 3;
        const float* xd = x + (size_t)(bt2 * NA + dn2) * 3;
        float c0 = xd[0] - xs[0], c1 = xd[1] - xs[1], c2 = xd[2] - xs[2];
        cds[buf ^ 1][tid * 3 + 0] = c0; cds[buf ^ 1][tid * 3 + 1] = c1;
        cds[buf ^ 1][tid * 3 + 2] = c2;
        dists[buf ^ 1][tid] = sqrtf(c0 * c0 + c1 * c1 + c2 * c2);
      }
    }
    __syncthreads();   // (B) all T reads done -> safe to overwrite
#pragma unroll
    for (int reg = 0; reg < 4; reg++) {
      int row = quad * 4 + reg;
      T[tswz(row, colW)] = (bf16)silu_f(acc2[reg] + bm2c);
    }
    __syncthreads();   // (C) messages ready

    // msgOut copy (waves 0-3, coalesced 16B chunks) + coord head (all waves)
    if (tid < 256) {
      int row = tid >> 4, cg = tid & 15;
      *(bf16x8*)&msgOut[(size_t)(t * 16 + row) * H + cg * 8] =
          *(const bf16x8*)&T[tswz(row, cg * 8)];
    }
    f32x4 acc3 = (f32x4){0.f, 0.f, 0.f, 0.f};
#pragma unroll
    for (int ks = 0; ks < 4; ks++) {
      bf16x8 aa = *(const bf16x8*)&T[tswz(l16, ks * 32 + quad * 8)];
      acc3 = __builtin_amdgcn_mfma_f32_16x16x32_bf16(aa, wc1f[ks], acc3, 0, 0, 0);
    }
    float cwp[4];
#pragma unroll
    for (int reg = 0; reg < 4; reg++)
      cwp[reg] = silu_f(acc3[reg] + bc1c) * wc2c;
#pragma unroll
    for (int reg = 0; reg < 4; reg++) {
      float s = cwp[reg];
      s += __shfl_xor(s, 1);
      s += __shfl_xor(s, 2);
      s += __shfl_xor(s, 4);
      s += __shfl_xor(s, 8);
      cwp[reg] = s;
    }
    if (l16 == 0) {
#pragma unroll
      for (int reg = 0; reg < 4; reg++)
        cwpart[w][quad * 4 + reg] = cwp[reg];
    }
    __syncthreads();   // (D) cwpart ready; also fences T reads vs next write

    if (tid < 16) {
      float cw = 0.f;
#pragma unroll
      for (int ww = 0; ww < 8; ww++) cw += cwpart[ww][tid];
      float inv = 1.0f / (dists[buf][tid] + 1e-8f);
      size_t R = (size_t)t * 16 + tid;
#pragma unroll
      for (int c = 0; c < 3; c++)
        updv[R * 3 + c] = cds[buf][tid * 3 + c] * inv * cw;
    }
    buf ^= 1;
  }
}

// ---------------- node kernel (2-phase: coalesced gather, N-split MFMA) ----
// Phase 1: thread = (row, 32B chunk). 8 threads fully cover each 256B msg
// row (coalesced); fp32 acc in regs -> bf16 agg tile in LDS. x_out fused.
// Phase 2: waves = 2 row-grp x 2 col-grp, acc[4] (16 AGPR) -> ~8 waves/SIMD.
__global__ __launch_bounds__(256, 6) void node_kernel(
    const float* __restrict__ h, const bf16* __restrict__ hb,
    const bf16* __restrict__ msg, const float* __restrict__ updv,
    const int* __restrict__ degI, const int* __restrict__ adj2,
    const bf16* __restrict__ Wn1p, const float* __restrict__ bn1,
    const bf16* __restrict__ Wn2p, const float* __restrict__ bn2,
    const float* __restrict__ x,
    float* __restrict__ hout, float* __restrict__ xout) {
  __shared__ __align__(16) bf16 Abuf[32 * 128];
  __shared__ __align__(16) bf16 Tbuf[32 * 128];

  const int tid = threadIdx.x, blk = blockIdx.x;

  // ---- phase 1: gather ----
  {
    const int row = tid >> 3, c8 = tid & 7;       // 32 rows x 8 chunks
    const int Rg = blk * 32 + row;                // batch*NA + atom
    const int atomA = Rg % NA, batA = Rg / NA;
    int deg = degI[atomA];
    if (deg > ADJ_CAP) deg = ADJ_CAP;
    const int* ap = adj2 + atomA * ADJ_CAP;
    float a16[16];
#pragma unroll
    for (int t = 0; t < 16; t++) a16[t] = 0.f;
    float sx = 0.f, sy = 0.f, sz = 0.f;
    int j = 0;
    for (; j + 2 <= deg; j += 2) {
      int ent0 = ap[j], ent1 = ap[j + 1];
      const bf16* m0 = msg + ((size_t)(ent0 >> 1) * 8 + batA) * H + c8 * 16;
      const bf16* m1 = msg + ((size_t)(ent1 >> 1) * 8 + batA) * H + c8 * 16;
      bf16x8 v0 = *(const bf16x8*)(m0);
      bf16x8 v1 = *(const bf16x8*)(m0 + 8);
      bf16x8 u0 = *(const bf16x8*)(m1);
      bf16x8 u1 = *(const bf16x8*)(m1 + 8);
      if (c8 == 0) {
        float sg0 = (ent0 & 1) ? 1.0f : -1.0f;
        float sg1 = (ent1 & 1) ? 1.0f : -1.0f;
        const float* uv0 = updv + ((size_t)(ent0 >> 1) * 8 + batA) * 3;
        const float* uv1 = updv + ((size_t)(ent1 >> 1) * 8 + batA) * 3;
        sx += sg0 * uv0[0] + sg1 * uv1[0];
        sy += sg0 * uv0[1] + sg1 * uv1[1];
        sz += sg0 * uv0[2] + sg1 * uv1[2];
      }
#pragma unroll
      for (int t = 0; t < 8; t++) {
        a16[t]     += (float)v0[t] + (float)u0[t];
        a16[8 + t] += (float)v1[t] + (float)u1[t];
      }
    }
    if (j < deg) {
      int ent0 = ap[j];
      const bf16* m0 = msg + ((size_t)(ent0 >> 1) * 8 + batA) * H + c8 * 16;
      bf16x8 v0 = *(const bf16x8*)(m0);
      bf16x8 v1 = *(const bf16x8*)(m0 + 8);
      if (c8 == 0) {
        float sg0 = (ent0 & 1) ? 1.0f : -1.0f;
        const float* uv0 = updv + ((size_t)(ent0 >> 1) * 8 + batA) * 3;
        sx += sg0 * uv0[0]; sy += sg0 * uv0[1]; sz += sg0 * uv0[2];
      }
#pragma unroll
      for (int t = 0; t < 8; t++) {
        a16[t]     += (float)v0[t];
        a16[8 + t] += (float)v1[t];
      }
    }
    if (c8 == 0) {   // x finalize
      float cnt = deg < 1 ? 1.0f : (float)deg;
      float inv = 1.0f / cnt;
      size_t o = (size_t)Rg * 3;
      xout[o + 0] = x[o + 0] + sx * inv;
      xout[o + 1] = x[o + 1] + sy * inv;
      xout[o + 2] = x[o + 2] + sz * inv;
    }
    bf16x8 w0, w1;
#pragma unroll
    for (int t = 0; t < 8; t++) { w0[t] = (bf16)a16[t]; w1[t] = (bf16)a16[8 + t]; }
    *(bf16x8*)&Abuf[tswz(row, c8 * 16)]     = w0;
    *(bf16x8*)&Abuf[tswz(row, c8 * 16 + 8)] = w1;
  }
  __syncthreads();   // agg tile ready

  // ---- phase 2: node MLP, N-split ----
  const int lane = tid & 63, wave = tid >> 6;
  const int quad = lane >> 4, l16 = lane & 15;
  const int rowG = (wave >> 1) * 16, colG = wave & 1, colBase = colG * 64;
  const int RgA = blk * 32 + rowG + l16;
  const bf16* hrow = hb + (size_t)RgA * H;
  const bf16x8* W1v = (const bf16x8*)Wn1p;
  const bf16x8* W2v = (const bf16x8*)Wn2p;

  f32x4 acc[4];
#pragma unroll
  for (int nt = 0; nt < 4; nt++) acc[nt] = (f32x4){0.f, 0.f, 0.f, 0.f};

  // layer-1 first half: h (bf16) register-direct from global
#pragma unroll
  for (int ks = 0; ks < 4; ks++) {
    bf16x8 a = *(const bf16x8*)(hrow + ks * 32 + quad * 8);
#pragma unroll
    for (int nt = 0; nt < 4; nt++) {
      bf16x8 b = W1v[((colG * 4 + nt) * 8 + ks) * 64 + lane];
      acc[nt] = __builtin_amdgcn_mfma_f32_16x16x32_bf16(a, b, acc[nt], 0, 0, 0);
    }
  }
  // layer-1 second half: aggregated from LDS
#pragma unroll
  for (int ks2 = 0; ks2 < 4; ks2++) {
    bf16x8 a = *(const bf16x8*)&Abuf[tswz(rowG + l16, ks2 * 32 + quad * 8)];
#pragma unroll
    for (int nt = 0; nt < 4; nt++) {
      bf16x8 b = W1v[((colG * 4 + nt) * 8 + 4 + ks2) * 64 + lane];
      acc[nt] = __builtin_amdgcn_mfma_f32_16x16x32_bf16(a, b, acc[nt], 0, 0, 0);
    }
  }
#pragma unroll
  for (int nt = 0; nt < 4; nt++) {
    int col = colBase + nt * 16 + l16;
    float bb = bn1[col];
#pragma unroll
    for (int reg = 0; reg < 4; reg++) {
      int row = rowG + quad * 4 + reg;
      Tbuf[tswz(row, col)] = (bf16)silu_f(acc[nt][reg] + bb);
    }
  }
  __syncthreads();   // T complete (both col halves)

#pragma unroll
  for (int nt = 0; nt < 4; nt++) acc[nt] = (f32x4){0.f, 0.f, 0.f, 0.f};
#pragma unroll
  for (int ks = 0; ks < 4; ks++) {
    bf16x8 a = *(const bf16x8*)&Tbuf[tswz(rowG + l16, ks * 32 + quad * 8)];
#pragma unroll
    for (int nt = 0; nt < 4; nt++) {
      bf16x8 b = W2v[((colG * 4 + nt) * 4 + ks) * 64 + lane];
      acc[nt] = __builtin_amdgcn_mfma_f32_16x16x32_bf16(a, b, acc[nt], 0, 0, 0);
    }
  }
#pragma unroll
  for (int nt = 0; nt < 4; nt++) {
    int col = colBase + nt * 16 + l16;
    float bb = bn2[col];
#pragma unroll
    for (int reg = 0; reg < 4; reg++) {
      size_t Ro = (size_t)blk * 32 + rowG + quad * 4 + reg;
      hout[Ro * H + col] = h[Ro * H + col] + acc[nt][reg] + bb;
    }
  }
}

extern "C" void kernel_launch(void* const* d_in, const int* in_sizes, int n_in,
                              void* d_out, int out_size, void* d_ws,
                              size_t ws_size, hipStream_t stream) {
  const float* h    = (const float*)d_in[0];
  const float* x    = (const float*)d_in[1];
  const int*  bonds = (const int*)d_in[2];
  const float* Wm1  = (const float*)d_in[3];
  const float* bm1  = (const float*)d_in[4];
  const float* Wm2  = (const float*)d_in[5];
  const float* bm2  = (const float*)d_in[6];
  const float* Wn1  = (const float*)d_in[7];
  const float* bn1  = (const float*)d_in[8];
  const float* Wn2  = (const float*)d_in[9];
  const float* bn2  = (const float*)d_in[10];
  const float* Wc1  = (const float*)d_in[11];
  const float* bc1  = (const float*)d_in[12];
  const float* Wc2  = (const float*)d_in[13];

  float* out  = (float*)d_out;
  float* hout = out;
  float* xout = out + (size_t)NBATCH * NA * H;

  char* ws = (char*)d_ws;
  // layout (bytes): NEED = 172,553,216 < 173,080,576 proven available.
  const size_t OFF_DEG  = 0;                        // NA int = 80,000
  const size_t OFF_W1   = 163840;                   // 65,536
  const size_t OFF_W2   = OFF_W1 + 65536;           // 32,768
  const size_t OFF_WN1  = OFF_W2 + 32768;           // 65,536
  const size_t OFF_WN2  = OFF_WN1 + 65536;          // 32,768
  const size_t OFF_WC1  = OFF_WN2 + 32768;          // 32,768 (ends 393,216)
  const size_t OFF_ADJ2 = 393216;                   // NA*32 int = 2,560,000
  const size_t OFF_UPDV = 2953216;                  // NB*8*3 f32 = 5,760,000
  const size_t OFF_HB   = 8713216;                  // 160000*128 bf16 = 40,960,000
  const size_t OFF_MSG  = 49673216;                 // NB*8*128 bf16 = 122,880,000

  int*   degI = (int*)(ws + OFF_DEG);
  bf16*  W1p  = (bf16*)(ws + OFF_W1);
  bf16*  W2p  = (bf16*)(ws + OFF_W2);
  bf16*  Wn1p = (bf16*)(ws + OFF_WN1);
  bf16*  Wn2p = (bf16*)(ws + OFF_WN2);
  bf16*  Wc1p = (bf16*)(ws + OFF_WC1);
  int*   adj2 = (int*)(ws + OFF_ADJ2);
  float* updv = (float*)(ws + OFF_UPDV);
  bf16*  hb   = (bf16*)(ws + OFF_HB);
  bf16*  msgB = (bf16*)(ws + OFF_MSG);

  (void)hipMemsetAsync(degI, 0, NA * sizeof(int), stream);

  cast_h<<<NBATCH * NA * H / 1024, 256, 0, stream>>>(h, hb);
  pack_w<<<128, 256, 0, stream>>>(Wm1, W1p, 256);
  pack_w<<<64, 256, 0, stream>>>(Wm2, W2p, 128);
  pack_w<<<128, 256, 0, stream>>>(Wn1, Wn1p, 256);
  pack_w<<<64, 256, 0, stream>>>(Wn2, Wn2p, 128);
  pack_w<<<64, 256, 0, stream>>>(Wc1, Wc1p, 128);

  build_adj2<<<(NB + 255) / 256, 256, 0, stream>>>(bonds, degI, adj2);

  msg_kernel<<<MSG_GRID, 512, 0, stream>>>(
      hb, x, bonds, W1p, bm1, W2p, bm2, Wm1 + 256 * H, Wc1p, bc1, Wc2,
      msgB, updv);
  node_kernel<<<NBATCH * NA / 32, 256, 0, stream>>>(
      h, hb, msgB, updv, degI, adj2, Wn1p, bn1, Wn2p, bn2, x,
      hout, xout);
}

// Round 7
// 509.942 us; speedup vs baseline: 1.1953x; 1.1953x over previous
//
#include <hip/hip_runtime.h>

// BondAwareEGNN fused layer — round 12.
//
// Round-11 post-mortem: persistent-W msg REGRESSED 230->330. Wrong theory:
// W-reload latency wasn't the stall. New structure broke what worked —
// 16 rows of work between 4 block-wide barriers (59 serial tiles), 512-thr
// lockstep at 46% occ, bank conflicts 2.4M->7.7M. Reverted.
//
// Round-12: msg = r10 N-split exact (known 230us, no spill). Node gets
// this round's change: phase-1 gather 4-way unrolled with int4 adj loads
// (adj2 rows 16B-aligned) -> deg-6 walk is 1 wide round + tail instead of
// 3 dependent rounds; 8 msg-row loads in flight. Regs ~65 < (256,6) cap.

#define H      128
#define NA     20000
#define NB     60000
#define NBATCH 8
#define ADJ_CAP 32

typedef __bf16 bf16;
typedef __bf16 bf16x4 __attribute__((ext_vector_type(4)));
typedef __bf16 bf16x8 __attribute__((ext_vector_type(8)));
typedef float  f32x4  __attribute__((ext_vector_type(4)));

__device__ __forceinline__ float silu_f(float v) {
  float e = __expf(-v);
  return v * __builtin_amdgcn_rcpf(1.0f + e);  // 1-ulp rcp; inf -> 0 ok
}

// XOR-swizzled index into a [R][128] bf16 tile. Row stride 256B (bank
// neutral); 16B chunk index XOR'd with row&7 rotates banks. Bijective per
// row; 8-element chunks stay contiguous so bf16x8 loads/stores still work.
__device__ __forceinline__ int tswz(int row, int col) {
  return (row << 7) + (((((col) >> 3) ^ (row & 7)) << 3) | (col & 7));
}

__global__ void cast_h(const float* __restrict__ src, bf16* __restrict__ dst) {
  int i = blockIdx.x * 256 + threadIdx.x;  // one float4 per thread
  float4 v = *(const float4*)(src + (size_t)i * 4);
  bf16x4 t = {(bf16)v.x, (bf16)v.y, (bf16)v.z, (bf16)v.w};
  *(bf16x4*)(dst + (size_t)i * 4) = t;
}

// fp32 KxN(128) row-major -> bf16 fragment-linear (8 bf16 per lane-frag).
__global__ void pack_w(const float* __restrict__ src, bf16* __restrict__ dst,
                       int K) {
  int i = blockIdx.x * 256 + threadIdx.x;
  if (i >= K * 128) return;
  int k = i >> 7, n = i & 127;
  int nt = n >> 4, ks = k >> 5;
  int lane = (((k >> 3) & 3) << 4) | (n & 15);
  int j = k & 7;
  int KS = K >> 5;
  dst[((((nt * KS + ks) * 64) + lane) << 3) + j] = (bf16)src[i];
}

// ---------------- adjacency build (fixed-capacity slots) ----------------
__global__ void build_adj2(const int* __restrict__ bonds,
                           int* __restrict__ degI, int* __restrict__ adj2) {
  int e = blockIdx.x * 256 + threadIdx.x;
  if (e >= NB) return;
  int s = bonds[2 * e], d = bonds[2 * e + 1];
  int p = atomicAdd(&degI[s], 1);
  if (p < ADJ_CAP) adj2[s * ADJ_CAP + p] = (e << 1);        // src: sign -
  p = atomicAdd(&degI[d], 1);
  if (p < ADJ_CAP) adj2[d * ADJ_CAP + p] = (e << 1) | 1;    // dst: sign +
}

// ---------------- message kernel (N-split: 16 rows x 64 cols per wave) ----
__global__ __launch_bounds__(256, 6) void msg_kernel(
    const bf16* __restrict__ hb, const float* __restrict__ x,
    const int* __restrict__ bonds,
    const bf16* __restrict__ W1p, const float* __restrict__ bm1,
    const bf16* __restrict__ W2p, const float* __restrict__ bm2,
    const float* __restrict__ w1c,   // Wm1 row 256 (dist row), fp32[128]
    const bf16* __restrict__ Wc1p, const float* __restrict__ bc1,
    const float* __restrict__ Wc2,
    bf16* __restrict__ msgOut, float* __restrict__ updv) {
  // [32][128] swizzled tile: T after layer-1, messages after layer-2.
  __shared__ __align__(16) bf16 Tbuf[32 * 128];
  __shared__ float cds[32 * 3];
  __shared__ float dists[32];
  __shared__ float bm1s[128], bm2s[128], w1cs[128], bc1s[128], wc2s[128];
  __shared__ float cwpart[2][32];

  const int tid = threadIdx.x, blk = blockIdx.x;

  if (tid < 32) {
    int Rg = blk * 32 + tid;
    int bond = Rg >> 3, batch = Rg & 7;
    int s = bonds[2 * bond], dn = bonds[2 * bond + 1];
    const float* xs = x + (size_t)(batch * NA + s) * 3;
    const float* xd = x + (size_t)(batch * NA + dn) * 3;
    float c0 = xd[0] - xs[0], c1 = xd[1] - xs[1], c2 = xd[2] - xs[2];
    cds[tid * 3 + 0] = c0; cds[tid * 3 + 1] = c1; cds[tid * 3 + 2] = c2;
    dists[tid] = sqrtf(c0 * c0 + c1 * c1 + c2 * c2);
  }
  if (tid < 128) {
    bm1s[tid] = bm1[tid]; bm2s[tid] = bm2[tid]; w1cs[tid] = w1c[tid];
    bc1s[tid] = bc1[tid]; wc2s[tid] = Wc2[tid];
  }
  __syncthreads();

  const int lane = tid & 63;
  const int quad = lane >> 4, l16 = lane & 15;
  const int wave = tid >> 6;
  const int rowBase = (wave >> 1) * 16;    // 2 row-groups
  const int colG = wave & 1;               // 2 col-groups
  const int colBase = colG * 64;
  const bf16x8* W1v = (const bf16x8*)W1p;
  const bf16x8* W2v = (const bf16x8*)W2p;
  const bf16x8* Wc1v = (const bf16x8*)Wc1p;

  // per-lane A-row metadata (row = rowBase + l16)
  const int RgA = blk * 32 + rowBase + l16;
  const int bondA = RgA >> 3, batA = RgA & 7;
  const bf16* hsrc = hb + (size_t)(batA * NA + bonds[2 * bondA]) * H;
  const bf16* hdst = hb + (size_t)(batA * NA + bonds[2 * bondA + 1]) * H;

  f32x4 acc[4];
#pragma unroll
  for (int nt = 0; nt < 4; nt++) acc[nt] = (f32x4){0.f, 0.f, 0.f, 0.f};

  // ---- layer 1: K = 256, A straight from global, B = this wave's W half --
#pragma unroll
  for (int ks = 0; ks < 4; ks++) {
    bf16x8 a = *(const bf16x8*)(hsrc + ks * 32 + quad * 8);
#pragma unroll
    for (int nt = 0; nt < 4; nt++) {
      bf16x8 b = W1v[((colG * 4 + nt) * 8 + ks) * 64 + lane];
      acc[nt] = __builtin_amdgcn_mfma_f32_16x16x32_bf16(a, b, acc[nt], 0, 0, 0);
    }
  }
#pragma unroll
  for (int ks = 4; ks < 8; ks++) {
    bf16x8 a = *(const bf16x8*)(hdst + (ks - 4) * 32 + quad * 8);
#pragma unroll
    for (int nt = 0; nt < 4; nt++) {
      bf16x8 b = W1v[((colG * 4 + nt) * 8 + ks) * 64 + lane];
      acc[nt] = __builtin_amdgcn_mfma_f32_16x16x32_bf16(a, b, acc[nt], 0, 0, 0);
    }
  }
  // t1 epilogue -> Tbuf
#pragma unroll
  for (int nt = 0; nt < 4; nt++) {
    int col = colBase + nt * 16 + l16;
    float bb = bm1s[col], wc = w1cs[col];
#pragma unroll
    for (int reg = 0; reg < 4; reg++) {
      int row = rowBase + quad * 4 + reg;
      float v = acc[nt][reg] + bb + dists[row] * wc;
      Tbuf[tswz(row, col)] = (bf16)silu_f(v);
    }
  }
  __syncthreads();   // T complete (both col halves)

  // ---- layer 2: K = 128 -> messages ----
#pragma unroll
  for (int nt = 0; nt < 4; nt++) acc[nt] = (f32x4){0.f, 0.f, 0.f, 0.f};
#pragma unroll
  for (int ks = 0; ks < 4; ks++) {
    bf16x8 a = *(const bf16x8*)&Tbuf[tswz(rowBase + l16, ks * 32 + quad * 8)];
#pragma unroll
    for (int nt = 0; nt < 4; nt++) {
      bf16x8 b = W2v[((colG * 4 + nt) * 4 + ks) * 64 + lane];
      acc[nt] = __builtin_amdgcn_mfma_f32_16x16x32_bf16(a, b, acc[nt], 0, 0, 0);
    }
  }
  __syncthreads();   // all layer-2 reads of T done; safe to overwrite
#pragma unroll
  for (int nt = 0; nt < 4; nt++) {
    int col = colBase + nt * 16 + l16;
    float bb = bm2s[col];
#pragma unroll
    for (int reg = 0; reg < 4; reg++) {
      int row = rowBase + quad * 4 + reg;
      Tbuf[tswz(row, col)] = (bf16)silu_f(acc[nt][reg] + bb);
    }
  }
  __syncthreads();   // messages complete

  // ---- coord head: silu(messages @ Wc1 + bc1) @ Wc2 ----
#pragma unroll
  for (int nt = 0; nt < 4; nt++) acc[nt] = (f32x4){0.f, 0.f, 0.f, 0.f};
#pragma unroll
  for (int ks = 0; ks < 4; ks++) {
    bf16x8 a = *(const bf16x8*)&Tbuf[tswz(rowBase + l16, ks * 32 + quad * 8)];
#pragma unroll
    for (int nt = 0; nt < 4; nt++) {
      bf16x8 b = Wc1v[((colG * 4 + nt) * 4 + ks) * 64 + lane];
      acc[nt] = __builtin_amdgcn_mfma_f32_16x16x32_bf16(a, b, acc[nt], 0, 0, 0);
    }
  }

  // copy this wave's 16 rows x 64 cols of messages to global (16B chunks)
#pragma unroll
  for (int i = 0; i < 2; i++) {
    int item = i * 64 + lane;
    int row = rowBase + (item >> 3);
    int cg = colG * 8 + (item & 7);
    *(bf16x8*)&msgOut[(size_t)(blk * 32 + row) * H + cg * 8] =
        *(const bf16x8*)&Tbuf[tswz(row, cg * 8)];
  }

  float cwp[4] = {0.f, 0.f, 0.f, 0.f};
#pragma unroll
  for (int nt = 0; nt < 4; nt++) {
    int col = colBase + nt * 16 + l16;
    float bb = bc1s[col], w2 = wc2s[col];
#pragma unroll
    for (int reg = 0; reg < 4; reg++)
      cwp[reg] += silu_f(acc[nt][reg] + bb) * w2;
  }
#pragma unroll
  for (int reg = 0; reg < 4; reg++) {
    float s = cwp[reg];
    s += __shfl_xor(s, 1);
    s += __shfl_xor(s, 2);
    s += __shfl_xor(s, 4);
    s += __shfl_xor(s, 8);
    cwp[reg] = s;
  }
  if (l16 == 0) {
#pragma unroll
    for (int reg = 0; reg < 4; reg++)
      cwpart[colG][rowBase + quad * 4 + reg] = cwp[reg];
  }
  __syncthreads();   // both col-halves' partials in
  if (colG == 0 && l16 == 0) {
#pragma unroll
    for (int reg = 0; reg < 4; reg++) {
      int row = rowBase + quad * 4 + reg;
      size_t Rg = (size_t)blk * 32 + row;
      float cw = cwpart[0][row] + cwpart[1][row];
      float inv = 1.0f / (dists[row] + 1e-8f);
#pragma unroll
      for (int c = 0; c < 3; c++)
        updv[Rg * 3 + c] = cds[row * 3 + c] * inv * cw;
    }
  }
}

// ---------------- node kernel (2-phase; 4-way int4 gather) ----------------
// Phase 1: thread = (row, 32B chunk). 8 threads cover each 256B msg row;
// adj entries fetched 4-at-a-time via int4 (adj2 rows 16B-aligned), 8 msg
// loads in flight. fp32 acc -> bf16 agg tile in LDS; x_out fused.
// Phase 2: waves = 2 row-grp x 2 col-grp, acc[4].
__global__ __launch_bounds__(256, 6) void node_kernel(
    const float* __restrict__ h, const bf16* __restrict__ hb,
    const bf16* __restrict__ msg, const float* __restrict__ updv,
    const int* __restrict__ degI, const int* __restrict__ adj2,
    const bf16* __restrict__ Wn1p, const float* __restrict__ bn1,
    const bf16* __restrict__ Wn2p, const float* __restrict__ bn2,
    const float* __restrict__ x,
    float* __restrict__ hout, float* __restrict__ xout) {
  __shared__ __align__(16) bf16 Abuf[32 * 128];
  __shared__ __align__(16) bf16 Tbuf[32 * 128];

  const int tid = threadIdx.x, blk = blockIdx.x;

  // ---- phase 1: gather ----
  {
    const int row = tid >> 3, c8 = tid & 7;       // 32 rows x 8 chunks
    const int Rg = blk * 32 + row;                // batch*NA + atom
    const int atomA = Rg % NA, batA = Rg / NA;
    int deg = degI[atomA];
    if (deg > ADJ_CAP) deg = ADJ_CAP;
    const int* ap = adj2 + atomA * ADJ_CAP;
    float a16[16];
#pragma unroll
    for (int t = 0; t < 16; t++) a16[t] = 0.f;
    float sx = 0.f, sy = 0.f, sz = 0.f;
    int j = 0;
    for (; j + 4 <= deg; j += 4) {
      int4 e4 = *(const int4*)&ap[j];   // one load, 4 entries
      const bf16* m0 = msg + ((size_t)(e4.x >> 1) * 8 + batA) * H + c8 * 16;
      const bf16* m1 = msg + ((size_t)(e4.y >> 1) * 8 + batA) * H + c8 * 16;
      const bf16* m2 = msg + ((size_t)(e4.z >> 1) * 8 + batA) * H + c8 * 16;
      const bf16* m3 = msg + ((size_t)(e4.w >> 1) * 8 + batA) * H + c8 * 16;
      bf16x8 v0 = *(const bf16x8*)(m0), v1 = *(const bf16x8*)(m0 + 8);
      bf16x8 u0 = *(const bf16x8*)(m1), u1 = *(const bf16x8*)(m1 + 8);
      bf16x8 p0 = *(const bf16x8*)(m2), p1 = *(const bf16x8*)(m2 + 8);
      bf16x8 q0 = *(const bf16x8*)(m3), q1 = *(const bf16x8*)(m3 + 8);
      if (c8 == 0) {
        float sg0 = (e4.x & 1) ? 1.0f : -1.0f;
        float sg1 = (e4.y & 1) ? 1.0f : -1.0f;
        float sg2 = (e4.z & 1) ? 1.0f : -1.0f;
        float sg3 = (e4.w & 1) ? 1.0f : -1.0f;
        const float* uv0 = updv + ((size_t)(e4.x >> 1) * 8 + batA) * 3;
        const float* uv1 = updv + ((size_t)(e4.y >> 1) * 8 + batA) * 3;
        const float* uv2 = updv + ((size_t)(e4.z >> 1) * 8 + batA) * 3;
        const float* uv3 = updv + ((size_t)(e4.w >> 1) * 8 + batA) * 3;
        sx += sg0 * uv0[0] + sg1 * uv1[0] + sg2 * uv2[0] + sg3 * uv3[0];
        sy += sg0 * uv0[1] + sg1 * uv1[1] + sg2 * uv2[1] + sg3 * uv3[1];
        sz += sg0 * uv0[2] + sg1 * uv1[2] + sg2 * uv2[2] + sg3 * uv3[2];
      }
#pragma unroll
      for (int t = 0; t < 8; t++) {
        a16[t]     += ((float)v0[t] + (float)u0[t]) + ((float)p0[t] + (float)q0[t]);
        a16[8 + t] += ((float)v1[t] + (float)u1[t]) + ((float)p1[t] + (float)q1[t]);
      }
    }
    for (; j < deg; j++) {
      int ent0 = ap[j];
      const bf16* m0 = msg + ((size_t)(ent0 >> 1) * 8 + batA) * H + c8 * 16;
      bf16x8 v0 = *(const bf16x8*)(m0);
      bf16x8 v1 = *(const bf16x8*)(m0 + 8);
      if (c8 == 0) {
        float sg0 = (ent0 & 1) ? 1.0f : -1.0f;
        const float* uv0 = updv + ((size_t)(ent0 >> 1) * 8 + batA) * 3;
        sx += sg0 * uv0[0]; sy += sg0 * uv0[1]; sz += sg0 * uv0[2];
      }
#pragma unroll
      for (int t = 0; t < 8; t++) {
        a16[t]     += (float)v0[t];
        a16[8 + t] += (float)v1[t];
      }
    }
    if (c8 == 0) {   // x finalize
      float cnt = deg < 1 ? 1.0f : (float)deg;
      float inv = 1.0f / cnt;
      size_t o = (size_t)Rg * 3;
      xout[o + 0] = x[o + 0] + sx * inv;
      xout[o + 1] = x[o + 1] + sy * inv;
      xout[o + 2] = x[o + 2] + sz * inv;
    }
    bf16x8 w0, w1;
#pragma unroll
    for (int t = 0; t < 8; t++) { w0[t] = (bf16)a16[t]; w1[t] = (bf16)a16[8 + t]; }
    *(bf16x8*)&Abuf[tswz(row, c8 * 16)]     = w0;
    *(bf16x8*)&Abuf[tswz(row, c8 * 16 + 8)] = w1;
  }
  __syncthreads();   // agg tile ready

  // ---- phase 2: node MLP, N-split ----
  const int lane = tid & 63, wave = tid >> 6;
  const int quad = lane >> 4, l16 = lane & 15;
  const int rowG = (wave >> 1) * 16, colG = wave & 1, colBase = colG * 64;
  const int RgA = blk * 32 + rowG + l16;
  const bf16* hrow = hb + (size_t)RgA * H;
  const bf16x8* W1v = (const bf16x8*)Wn1p;
  const bf16x8* W2v = (const bf16x8*)Wn2p;

  f32x4 acc[4];
#pragma unroll
  for (int nt = 0; nt < 4; nt++) acc[nt] = (f32x4){0.f, 0.f, 0.f, 0.f};

  // layer-1 first half: h (bf16) register-direct from global
#pragma unroll
  for (int ks = 0; ks < 4; ks++) {
    bf16x8 a = *(const bf16x8*)(hrow + ks * 32 + quad * 8);
#pragma unroll
    for (int nt = 0; nt < 4; nt++) {
      bf16x8 b = W1v[((colG * 4 + nt) * 8 + ks) * 64 + lane];
      acc[nt] = __builtin_amdgcn_mfma_f32_16x16x32_bf16(a, b, acc[nt], 0, 0, 0);
    }
  }
  // layer-1 second half: aggregated from LDS
#pragma unroll
  for (int ks2 = 0; ks2 < 4; ks2++) {
    bf16x8 a = *(const bf16x8*)&Abuf[tswz(rowG + l16, ks2 * 32 + quad * 8)];
#pragma unroll
    for (int nt = 0; nt < 4; nt++) {
      bf16x8 b = W1v[((colG * 4 + nt) * 8 + 4 + ks2) * 64 + lane];
      acc[nt] = __builtin_amdgcn_mfma_f32_16x16x32_bf16(a, b, acc[nt], 0, 0, 0);
    }
  }
#pragma unroll
  for (int nt = 0; nt < 4; nt++) {
    int col = colBase + nt * 16 + l16;
    float bb = bn1[col];
#pragma unroll
    for (int reg = 0; reg < 4; reg++) {
      int row = rowG + quad * 4 + reg;
      Tbuf[tswz(row, col)] = (bf16)silu_f(acc[nt][reg] + bb);
    }
  }
  __syncthreads();   // T complete (both col halves)

#pragma unroll
  for (int nt = 0; nt < 4; nt++) acc[nt] = (f32x4){0.f, 0.f, 0.f, 0.f};
#pragma unroll
  for (int ks = 0; ks < 4; ks++) {
    bf16x8 a = *(const bf16x8*)&Tbuf[tswz(rowG + l16, ks * 32 + quad * 8)];
#pragma unroll
    for (int nt = 0; nt < 4; nt++) {
      bf16x8 b = W2v[((colG * 4 + nt) * 4 + ks) * 64 + lane];
      acc[nt] = __builtin_amdgcn_mfma_f32_16x16x32_bf16(a, b, acc[nt], 0, 0, 0);
    }
  }
#pragma unroll
  for (int nt = 0; nt < 4; nt++) {
    int col = colBase + nt * 16 + l16;
    float bb = bn2[col];
#pragma unroll
    for (int reg = 0; reg < 4; reg++) {
      size_t Ro = (size_t)blk * 32 + rowG + quad * 4 + reg;
      hout[Ro * H + col] = h[Ro * H + col] + acc[nt][reg] + bb;
    }
  }
}

extern "C" void kernel_launch(void* const* d_in, const int* in_sizes, int n_in,
                              void* d_out, int out_size, void* d_ws,
                              size_t ws_size, hipStream_t stream) {
  const float* h    = (const float*)d_in[0];
  const float* x    = (const float*)d_in[1];
  const int*  bonds = (const int*)d_in[2];
  const float* Wm1  = (const float*)d_in[3];
  const float* bm1  = (const float*)d_in[4];
  const float* Wm2  = (const float*)d_in[5];
  const float* bm2  = (const float*)d_in[6];
  const float* Wn1  = (const float*)d_in[7];
  const float* bn1  = (const float*)d_in[8];
  const float* Wn2  = (const float*)d_in[9];
  const float* bn2  = (const float*)d_in[10];
  const float* Wc1  = (const float*)d_in[11];
  const float* bc1  = (const float*)d_in[12];
  const float* Wc2  = (const float*)d_in[13];

  float* out  = (float*)d_out;
  float* hout = out;
  float* xout = out + (size_t)NBATCH * NA * H;

  char* ws = (char*)d_ws;
  // layout (bytes): NEED = 172,553,216 < 173,080,576 proven available.
  const size_t OFF_DEG  = 0;                        // NA int = 80,000
  const size_t OFF_W1   = 163840;                   // 65,536
  const size_t OFF_W2   = OFF_W1 + 65536;           // 32,768
  const size_t OFF_WN1  = OFF_W2 + 32768;           // 65,536
  const size_t OFF_WN2  = OFF_WN1 + 65536;          // 32,768
  const size_t OFF_WC1  = OFF_WN2 + 32768;          // 32,768 (ends 393,216)
  const size_t OFF_ADJ2 = 393216;                   // NA*32 int = 2,560,000
  const size_t OFF_UPDV = 2953216;                  // NB*8*3 f32 = 5,760,000
  const size_t OFF_HB   = 8713216;                  // 160000*128 bf16 = 40,960,000
  const size_t OFF_MSG  = 49673216;                 // NB*8*128 bf16 = 122,880,000

  int*   degI = (int*)(ws + OFF_DEG);
  bf16*  W1p  = (bf16*)(ws + OFF_W1);
  bf16*  W2p  = (bf16*)(ws + OFF_W2);
  bf16*  Wn1p = (bf16*)(ws + OFF_WN1);
  bf16*  Wn2p = (bf16*)(ws + OFF_WN2);
  bf16*  Wc1p = (bf16*)(ws + OFF_WC1);
  int*   adj2 = (int*)(ws + OFF_ADJ2);
  float* updv = (float*)(ws + OFF_UPDV);
  bf16*  hb   = (bf16*)(ws + OFF_HB);
  bf16*  msgB = (bf16*)(ws + OFF_MSG);

  (void)hipMemsetAsync(degI, 0, NA * sizeof(int), stream);

  cast_h<<<NBATCH * NA * H / 1024, 256, 0, stream>>>(h, hb);
  pack_w<<<128, 256, 0, stream>>>(Wm1, W1p, 256);
  pack_w<<<64, 256, 0, stream>>>(Wm2, W2p, 128);
  pack_w<<<128, 256, 0, stream>>>(Wn1, Wn1p, 256);
  pack_w<<<64, 256, 0, stream>>>(Wn2, Wn2p, 128);
  pack_w<<<64, 256, 0, stream>>>(Wc1, Wc1p, 128);

  build_adj2<<<(NB + 255) / 256, 256, 0, stream>>>(bonds, degI, adj2);

  msg_kernel<<<NB * NBATCH / 32, 256, 0, stream>>>(
      hb, x, bonds, W1p, bm1, W2p, bm2, Wm1 + 256 * H, Wc1p, bc1, Wc2,
      msgB, updv);
  node_kernel<<<NBATCH * NA / 32, 256, 0, stream>>>(
      h, hb, msgB, updv, degI, adj2, Wn1p, bn1, Wn2p, bn2, x,
      hout, xout);
}

// Round 8
// 503.180 us; speedup vs baseline: 1.2114x; 1.0134x over previous
//
#include <hip/hip_runtime.h>

// BondAwareEGNN fused layer — round 13.
//
// Round-12 post-mortem: msg revert OK (224us). node int4 gather neutral ->
// adj-entry load wasn't the chain bottleneck. msg per-wave B:MFMA is 1:1
// (32 L2 W-loads feed 32 MFMAs) — r8 tried M=32 full-width and spilled
// (64 AGPR). N-split budget: M=32 x N=64 needs only 32 AGPR.
//
// Round-13:
//   1. msg: M=32 x N=64 per wave. Block = 64 rows, 4 waves (2 row-grp x
//      2 col-grp), acc[4]x2 (32 AGPR), B:MFMA 1:2, barriers per row
//      halved, ~80-90 regs under (256,4)'s 128 cap. Spill guard: WRITE
//      must stay ~126MB.
//   2. node: kill the degI->adj serial level. adj2 pre-filled with NULL
//      entries (bond=NB -> dedicated zeroed msg row + zeroed updv slot);
//      first 8 entries processed unconditionally (deg, adj[0:3], adj[4:7]
//      all in flight together); tail loop only for deg>8 (~15%).

#define H      128
#define NA     20000
#define NB     60000
#define NBATCH 8
#define ADJ_CAP 32
#define NULL_ENT (NB << 1)   // bond NB = zeroed msg/updv row

typedef __bf16 bf16;
typedef __bf16 bf16x4 __attribute__((ext_vector_type(4)));
typedef __bf16 bf16x8 __attribute__((ext_vector_type(8)));
typedef float  f32x4  __attribute__((ext_vector_type(4)));

__device__ __forceinline__ float silu_f(float v) {
  float e = __expf(-v);
  return v * __builtin_amdgcn_rcpf(1.0f + e);  // 1-ulp rcp; inf -> 0 ok
}

// XOR-swizzled index into a [R][128] bf16 tile. Row stride 256B (bank
// neutral); 16B chunk index XOR'd with row&7 rotates banks. Bijective per
// row; 8-element chunks stay contiguous so bf16x8 loads/stores still work.
__device__ __forceinline__ int tswz(int row, int col) {
  return (row << 7) + (((((col) >> 3) ^ (row & 7)) << 3) | (col & 7));
}

__global__ void cast_h(const float* __restrict__ src, bf16* __restrict__ dst) {
  int i = blockIdx.x * 256 + threadIdx.x;  // one float4 per thread
  float4 v = *(const float4*)(src + (size_t)i * 4);
  bf16x4 t = {(bf16)v.x, (bf16)v.y, (bf16)v.z, (bf16)v.w};
  *(bf16x4*)(dst + (size_t)i * 4) = t;
}

// fp32 KxN(128) row-major -> bf16 fragment-linear (8 bf16 per lane-frag).
__global__ void pack_w(const float* __restrict__ src, bf16* __restrict__ dst,
                       int K) {
  int i = blockIdx.x * 256 + threadIdx.x;
  if (i >= K * 128) return;
  int k = i >> 7, n = i & 127;
  int nt = n >> 4, ks = k >> 5;
  int lane = (((k >> 3) & 3) << 4) | (n & 15);
  int j = k & 7;
  int KS = K >> 5;
  dst[((((nt * KS + ks) * 64) + lane) << 3) + j] = (bf16)src[i];
}

// ---------------- adjacency init + build (fixed-capacity slots) ----------
__global__ void init_adj(int* __restrict__ degI, int* __restrict__ adj2) {
  int i = blockIdx.x * 256 + threadIdx.x;
  if (i < NA) degI[i] = 0;
  if (i < NA * ADJ_CAP) adj2[i] = NULL_ENT;
}

__global__ void build_adj2(const int* __restrict__ bonds,
                           int* __restrict__ degI, int* __restrict__ adj2) {
  int e = blockIdx.x * 256 + threadIdx.x;
  if (e >= NB) return;
  int s = bonds[2 * e], d = bonds[2 * e + 1];
  int p = atomicAdd(&degI[s], 1);
  if (p < ADJ_CAP) adj2[s * ADJ_CAP + p] = (e << 1);        // src: sign -
  p = atomicAdd(&degI[d], 1);
  if (p < ADJ_CAP) adj2[d * ADJ_CAP + p] = (e << 1) | 1;    // dst: sign +
}

// ---------------- message kernel (M=32 x N=64 per wave) ----------------
__global__ __launch_bounds__(256, 4) void msg_kernel(
    const bf16* __restrict__ hb, const float* __restrict__ x,
    const int* __restrict__ bonds,
    const bf16* __restrict__ W1p, const float* __restrict__ bm1,
    const bf16* __restrict__ W2p, const float* __restrict__ bm2,
    const float* __restrict__ w1c,   // Wm1 row 256 (dist row), fp32[128]
    const bf16* __restrict__ Wc1p, const float* __restrict__ bc1,
    const float* __restrict__ Wc2,
    bf16* __restrict__ msgOut, float* __restrict__ updv) {
  // [64][128] swizzled tile: T after layer-1, messages after layer-2.
  __shared__ __align__(16) bf16 Tbuf[64 * 128];
  __shared__ float cds[64 * 3];
  __shared__ float dists[64];
  __shared__ float bm1s[128], bm2s[128], w1cs[128], bc1s[128], wc2s[128];
  __shared__ float cwpart[2][64];

  const int tid = threadIdx.x, blk = blockIdx.x;

  if (tid < 64) {
    int Rg = blk * 64 + tid;
    int bond = Rg >> 3, batch = Rg & 7;
    int s = bonds[2 * bond], dn = bonds[2 * bond + 1];
    const float* xs = x + (size_t)(batch * NA + s) * 3;
    const float* xd = x + (size_t)(batch * NA + dn) * 3;
    float c0 = xd[0] - xs[0], c1 = xd[1] - xs[1], c2 = xd[2] - xs[2];
    cds[tid * 3 + 0] = c0; cds[tid * 3 + 1] = c1; cds[tid * 3 + 2] = c2;
    dists[tid] = sqrtf(c0 * c0 + c1 * c1 + c2 * c2);
  }
  if (tid < 128) {
    bm1s[tid] = bm1[tid]; bm2s[tid] = bm2[tid]; w1cs[tid] = w1c[tid];
    bc1s[tid] = bc1[tid]; wc2s[tid] = Wc2[tid];
  }
  __syncthreads();

  const int lane = tid & 63;
  const int quad = lane >> 4, l16 = lane & 15;
  const int wave = tid >> 6;
  const int rowBase = (wave >> 1) * 32;    // 2 row-groups of 32
  const int colG = wave & 1;               // 2 col-groups of 64
  const int colBase = colG * 64;
  const bf16x8* W1v = (const bf16x8*)W1p;
  const bf16x8* W2v = (const bf16x8*)W2p;
  const bf16x8* Wc1v = (const bf16x8*)Wc1p;

  // per-lane A-row metadata, two row sets (rowBase+l16, rowBase+16+l16)
  const int Rg0 = blk * 64 + rowBase + l16;
  const int bn0 = Rg0 >> 3, bat0 = Rg0 & 7;
  const bf16* hs0 = hb + (size_t)(bat0 * NA + bonds[2 * bn0]) * H;
  const bf16* hd0 = hb + (size_t)(bat0 * NA + bonds[2 * bn0 + 1]) * H;
  const int Rg1 = Rg0 + 16;
  const int bn1_ = Rg1 >> 3, bat1 = Rg1 & 7;
  const bf16* hs1 = hb + (size_t)(bat1 * NA + bonds[2 * bn1_]) * H;
  const bf16* hd1 = hb + (size_t)(bat1 * NA + bonds[2 * bn1_ + 1]) * H;

  f32x4 acc0[4], acc1[4];
#pragma unroll
  for (int nt = 0; nt < 4; nt++) {
    acc0[nt] = (f32x4){0.f, 0.f, 0.f, 0.f};
    acc1[nt] = (f32x4){0.f, 0.f, 0.f, 0.f};
  }

  // ---- layer 1: K = 256; each B fragment feeds 2 MFMAs ----
#pragma unroll
  for (int ks = 0; ks < 4; ks++) {
    bf16x8 a0 = *(const bf16x8*)(hs0 + ks * 32 + quad * 8);
    bf16x8 a1 = *(const bf16x8*)(hs1 + ks * 32 + quad * 8);
#pragma unroll
    for (int nt = 0; nt < 4; nt++) {
      bf16x8 b = W1v[((colG * 4 + nt) * 8 + ks) * 64 + lane];
      acc0[nt] = __builtin_amdgcn_mfma_f32_16x16x32_bf16(a0, b, acc0[nt], 0, 0, 0);
      acc1[nt] = __builtin_amdgcn_mfma_f32_16x16x32_bf16(a1, b, acc1[nt], 0, 0, 0);
    }
  }
#pragma unroll
  for (int ks = 4; ks < 8; ks++) {
    bf16x8 a0 = *(const bf16x8*)(hd0 + (ks - 4) * 32 + quad * 8);
    bf16x8 a1 = *(const bf16x8*)(hd1 + (ks - 4) * 32 + quad * 8);
#pragma unroll
    for (int nt = 0; nt < 4; nt++) {
      bf16x8 b = W1v[((colG * 4 + nt) * 8 + ks) * 64 + lane];
      acc0[nt] = __builtin_amdgcn_mfma_f32_16x16x32_bf16(a0, b, acc0[nt], 0, 0, 0);
      acc1[nt] = __builtin_amdgcn_mfma_f32_16x16x32_bf16(a1, b, acc1[nt], 0, 0, 0);
    }
  }
  // t1 epilogue -> Tbuf
#pragma unroll
  for (int nt = 0; nt < 4; nt++) {
    int col = colBase + nt * 16 + l16;
    float bb = bm1s[col], wc = w1cs[col];
#pragma unroll
    for (int reg = 0; reg < 4; reg++) {
      int row0 = rowBase + quad * 4 + reg;
      int row1 = row0 + 16;
      Tbuf[tswz(row0, col)] = (bf16)silu_f(acc0[nt][reg] + bb + dists[row0] * wc);
      Tbuf[tswz(row1, col)] = (bf16)silu_f(acc1[nt][reg] + bb + dists[row1] * wc);
    }
  }
  __syncthreads();   // T complete

  // ---- layer 2: K = 128 -> messages ----
#pragma unroll
  for (int nt = 0; nt < 4; nt++) {
    acc0[nt] = (f32x4){0.f, 0.f, 0.f, 0.f};
    acc1[nt] = (f32x4){0.f, 0.f, 0.f, 0.f};
  }
#pragma unroll
  for (int ks = 0; ks < 4; ks++) {
    bf16x8 a0 = *(const bf16x8*)&Tbuf[tswz(rowBase + l16, ks * 32 + quad * 8)];
    bf16x8 a1 = *(const bf16x8*)&Tbuf[tswz(rowBase + 16 + l16, ks * 32 + quad * 8)];
#pragma unroll
    for (int nt = 0; nt < 4; nt++) {
      bf16x8 b = W2v[((colG * 4 + nt) * 4 + ks) * 64 + lane];
      acc0[nt] = __builtin_amdgcn_mfma_f32_16x16x32_bf16(a0, b, acc0[nt], 0, 0, 0);
      acc1[nt] = __builtin_amdgcn_mfma_f32_16x16x32_bf16(a1, b, acc1[nt], 0, 0, 0);
    }
  }
  __syncthreads();   // all T reads done; safe to overwrite
#pragma unroll
  for (int nt = 0; nt < 4; nt++) {
    int col = colBase + nt * 16 + l16;
    float bb = bm2s[col];
#pragma unroll
    for (int reg = 0; reg < 4; reg++) {
      int row0 = rowBase + quad * 4 + reg;
      int row1 = row0 + 16;
      Tbuf[tswz(row0, col)] = (bf16)silu_f(acc0[nt][reg] + bb);
      Tbuf[tswz(row1, col)] = (bf16)silu_f(acc1[nt][reg] + bb);
    }
  }
  __syncthreads();   // messages complete

  // ---- coord head ----
#pragma unroll
  for (int nt = 0; nt < 4; nt++) {
    acc0[nt] = (f32x4){0.f, 0.f, 0.f, 0.f};
    acc1[nt] = (f32x4){0.f, 0.f, 0.f, 0.f};
  }
#pragma unroll
  for (int ks = 0; ks < 4; ks++) {
    bf16x8 a0 = *(const bf16x8*)&Tbuf[tswz(rowBase + l16, ks * 32 + quad * 8)];
    bf16x8 a1 = *(const bf16x8*)&Tbuf[tswz(rowBase + 16 + l16, ks * 32 + quad * 8)];
#pragma unroll
    for (int nt = 0; nt < 4; nt++) {
      bf16x8 b = Wc1v[((colG * 4 + nt) * 4 + ks) * 64 + lane];
      acc0[nt] = __builtin_amdgcn_mfma_f32_16x16x32_bf16(a0, b, acc0[nt], 0, 0, 0);
      acc1[nt] = __builtin_amdgcn_mfma_f32_16x16x32_bf16(a1, b, acc1[nt], 0, 0, 0);
    }
  }

  // copy 64 message rows to global (4 x 16B chunks per thread, coalesced)
#pragma unroll
  for (int i = 0; i < 4; i++) {
    int item = i * 256 + tid;
    int row = item >> 4, cg = item & 15;
    *(bf16x8*)&msgOut[(size_t)(blk * 64 + row) * H + cg * 8] =
        *(const bf16x8*)&Tbuf[tswz(row, cg * 8)];
  }

  float cwp0[4] = {0.f, 0.f, 0.f, 0.f};
  float cwp1[4] = {0.f, 0.f, 0.f, 0.f};
#pragma unroll
  for (int nt = 0; nt < 4; nt++) {
    int col = colBase + nt * 16 + l16;
    float bb = bc1s[col], w2 = wc2s[col];
#pragma unroll
    for (int reg = 0; reg < 4; reg++) {
      cwp0[reg] += silu_f(acc0[nt][reg] + bb) * w2;
      cwp1[reg] += silu_f(acc1[nt][reg] + bb) * w2;
    }
  }
#pragma unroll
  for (int reg = 0; reg < 4; reg++) {
    float s0 = cwp0[reg], s1 = cwp1[reg];
    s0 += __shfl_xor(s0, 1); s1 += __shfl_xor(s1, 1);
    s0 += __shfl_xor(s0, 2); s1 += __shfl_xor(s1, 2);
    s0 += __shfl_xor(s0, 4); s1 += __shfl_xor(s1, 4);
    s0 += __shfl_xor(s0, 8); s1 += __shfl_xor(s1, 8);
    cwp0[reg] = s0; cwp1[reg] = s1;
  }
  if (l16 == 0) {
#pragma unroll
    for (int reg = 0; reg < 4; reg++) {
      int row0 = rowBase + quad * 4 + reg;
      cwpart[colG][row0] = cwp0[reg];
      cwpart[colG][row0 + 16] = cwp1[reg];
    }
  }
  __syncthreads();   // both col-halves' partials in
  if (colG == 0 && l16 == 0) {
#pragma unroll
    for (int reg = 0; reg < 4; reg++) {
#pragma unroll
      for (int rs = 0; rs < 2; rs++) {
        int row = rowBase + quad * 4 + reg + rs * 16;
        size_t Rg = (size_t)blk * 64 + row;
        float cw = cwpart[0][row] + cwpart[1][row];
        float inv = 1.0f / (dists[row] + 1e-8f);
#pragma unroll
        for (int c = 0; c < 3; c++)
          updv[Rg * 3 + c] = cds[row * 3 + c] * inv * cw;
      }
    }
  }
}

// ---------------- node kernel (2-phase; null-padded parallel gather) ------
__global__ __launch_bounds__(256, 6) void node_kernel(
    const float* __restrict__ h, const bf16* __restrict__ hb,
    const bf16* __restrict__ msg, const float* __restrict__ updv,
    const int* __restrict__ degI, const int* __restrict__ adj2,
    const bf16* __restrict__ Wn1p, const float* __restrict__ bn1,
    const bf16* __restrict__ Wn2p, const float* __restrict__ bn2,
    const float* __restrict__ x,
    float* __restrict__ hout, float* __restrict__ xout) {
  __shared__ __align__(16) bf16 Abuf[32 * 128];
  __shared__ __align__(16) bf16 Tbuf[32 * 128];

  const int tid = threadIdx.x, blk = blockIdx.x;

  // ---- phase 1: gather ----
  {
    const int row = tid >> 3, c8 = tid & 7;       // 32 rows x 8 chunks
    const int Rg = blk * 32 + row;                // batch*NA + atom
    const int atomA = Rg % NA, batA = Rg / NA;
    const int* ap = adj2 + atomA * ADJ_CAP;
    // three independent loads in flight together (null-padded adj2 makes
    // the first 8 entries unconditionally processable)
    int deg = degI[atomA];
    int4 eA = *(const int4*)&ap[0];
    int4 eB = *(const int4*)&ap[4];
    if (deg > ADJ_CAP) deg = ADJ_CAP;

    float a16[16];
#pragma unroll
    for (int t = 0; t < 16; t++) a16[t] = 0.f;
    float sx = 0.f, sy = 0.f, sz = 0.f;

    auto gather4 = [&](int4 e4) {
      const bf16* m0 = msg + ((size_t)(e4.x >> 1) * 8 + batA) * H + c8 * 16;
      const bf16* m1 = msg + ((size_t)(e4.y >> 1) * 8 + batA) * H + c8 * 16;
      const bf16* m2 = msg + ((size_t)(e4.z >> 1) * 8 + batA) * H + c8 * 16;
      const bf16* m3 = msg + ((size_t)(e4.w >> 1) * 8 + batA) * H + c8 * 16;
      bf16x8 v0 = *(const bf16x8*)(m0), v1 = *(const bf16x8*)(m0 + 8);
      bf16x8 u0 = *(const bf16x8*)(m1), u1 = *(const bf16x8*)(m1 + 8);
      bf16x8 p0 = *(const bf16x8*)(m2), p1 = *(const bf16x8*)(m2 + 8);
      bf16x8 q0 = *(const bf16x8*)(m3), q1 = *(const bf16x8*)(m3 + 8);
      if (c8 == 0) {
        float sg0 = (e4.x & 1) ? 1.0f : -1.0f;
        float sg1 = (e4.y & 1) ? 1.0f : -1.0f;
        float sg2 = (e4.z & 1) ? 1.0f : -1.0f;
        float sg3 = (e4.w & 1) ? 1.0f : -1.0f;
        const float* uv0 = updv + ((size_t)(e4.x >> 1) * 8 + batA) * 3;
        const float* uv1 = updv + ((size_t)(e4.y >> 1) * 8 + batA) * 3;
        const float* uv2 = updv + ((size_t)(e4.z >> 1) * 8 + batA) * 3;
        const float* uv3 = updv + ((size_t)(e4.w >> 1) * 8 + batA) * 3;
        sx += sg0 * uv0[0] + sg1 * uv1[0] + sg2 * uv2[0] + sg3 * uv3[0];
        sy += sg0 * uv0[1] + sg1 * uv1[1] + sg2 * uv2[1] + sg3 * uv3[1];
        sz += sg0 * uv0[2] + sg1 * uv1[2] + sg2 * uv2[2] + sg3 * uv3[2];
      }
#pragma unroll
      for (int t = 0; t < 8; t++) {
        a16[t]     += ((float)v0[t] + (float)u0[t]) + ((float)p0[t] + (float)q0[t]);
        a16[8 + t] += ((float)v1[t] + (float)u1[t]) + ((float)p1[t] + (float)q1[t]);
      }
    };

    gather4(eA);
    gather4(eB);
    int j = 8;
    for (; j + 4 <= deg; j += 4) gather4(*(const int4*)&ap[j]);
    for (; j < deg; j++) {
      int ent0 = ap[j];
      const bf16* m0 = msg + ((size_t)(ent0 >> 1) * 8 + batA) * H + c8 * 16;
      bf16x8 v0 = *(const bf16x8*)(m0);
      bf16x8 v1 = *(const bf16x8*)(m0 + 8);
      if (c8 == 0) {
        float sg0 = (ent0 & 1) ? 1.0f : -1.0f;
        const float* uv0 = updv + ((size_t)(ent0 >> 1) * 8 + batA) * 3;
        sx += sg0 * uv0[0]; sy += sg0 * uv0[1]; sz += sg0 * uv0[2];
      }
#pragma unroll
      for (int t = 0; t < 8; t++) {
        a16[t]     += (float)v0[t];
        a16[8 + t] += (float)v1[t];
      }
    }
    if (c8 == 0) {   // x finalize
      float cnt = deg < 1 ? 1.0f : (float)deg;
      float inv = 1.0f / cnt;
      size_t o = (size_t)Rg * 3;
      xout[o + 0] = x[o + 0] + sx * inv;
      xout[o + 1] = x[o + 1] + sy * inv;
      xout[o + 2] = x[o + 2] + sz * inv;
    }
    bf16x8 w0, w1;
#pragma unroll
    for (int t = 0; t < 8; t++) { w0[t] = (bf16)a16[t]; w1[t] = (bf16)a16[8 + t]; }
    *(bf16x8*)&Abuf[tswz(row, c8 * 16)]     = w0;
    *(bf16x8*)&Abuf[tswz(row, c8 * 16 + 8)] = w1;
  }
  __syncthreads();   // agg tile ready

  // ---- phase 2: node MLP, N-split ----
  const int lane = tid & 63, wave = tid >> 6;
  const int quad = lane >> 4, l16 = lane & 15;
  const int rowG = (wave >> 1) * 16, colG = wave & 1, colBase = colG * 64;
  const int RgA = blk * 32 + rowG + l16;
  const bf16* hrow = hb + (size_t)RgA * H;
  const bf16x8* W1v = (const bf16x8*)Wn1p;
  const bf16x8* W2v = (const bf16x8*)Wn2p;

  f32x4 acc[4];
#pragma unroll
  for (int nt = 0; nt < 4; nt++) acc[nt] = (f32x4){0.f, 0.f, 0.f, 0.f};

  // layer-1 first half: h (bf16) register-direct from global
#pragma unroll
  for (int ks = 0; ks < 4; ks++) {
    bf16x8 a = *(const bf16x8*)(hrow + ks * 32 + quad * 8);
#pragma unroll
    for (int nt = 0; nt < 4; nt++) {
      bf16x8 b = W1v[((colG * 4 + nt) * 8 + ks) * 64 + lane];
      acc[nt] = __builtin_amdgcn_mfma_f32_16x16x32_bf16(a, b, acc[nt], 0, 0, 0);
    }
  }
  // layer-1 second half: aggregated from LDS
#pragma unroll
  for (int ks2 = 0; ks2 < 4; ks2++) {
    bf16x8 a = *(const bf16x8*)&Abuf[tswz(rowG + l16, ks2 * 32 + quad * 8)];
#pragma unroll
    for (int nt = 0; nt < 4; nt++) {
      bf16x8 b = W1v[((colG * 4 + nt) * 8 + 4 + ks2) * 64 + lane];
      acc[nt] = __builtin_amdgcn_mfma_f32_16x16x32_bf16(a, b, acc[nt], 0, 0, 0);
    }
  }
#pragma unroll
  for (int nt = 0; nt < 4; nt++) {
    int col = colBase + nt * 16 + l16;
    float bb = bn1[col];
#pragma unroll
    for (int reg = 0; reg < 4; reg++) {
      int row = rowG + quad * 4 + reg;
      Tbuf[tswz(row, col)] = (bf16)silu_f(acc[nt][reg] + bb);
    }
  }
  __syncthreads();   // T complete (both col halves)

#pragma unroll
  for (int nt = 0; nt < 4; nt++) acc[nt] = (f32x4){0.f, 0.f, 0.f, 0.f};
#pragma unroll
  for (int ks = 0; ks < 4; ks++) {
    bf16x8 a = *(const bf16x8*)&Tbuf[tswz(rowG + l16, ks * 32 + quad * 8)];
#pragma unroll
    for (int nt = 0; nt < 4; nt++) {
      bf16x8 b = W2v[((colG * 4 + nt) * 4 + ks) * 64 + lane];
      acc[nt] = __builtin_amdgcn_mfma_f32_16x16x32_bf16(a, b, acc[nt], 0, 0, 0);
    }
  }
#pragma unroll
  for (int nt = 0; nt < 4; nt++) {
    int col = colBase + nt * 16 + l16;
    float bb = bn2[col];
#pragma unroll
    for (int reg = 0; reg < 4; reg++) {
      size_t Ro = (size_t)blk * 32 + rowG + quad * 4 + reg;
      hout[Ro * H + col] = h[Ro * H + col] + acc[nt][reg] + bb;
    }
  }
}

extern "C" void kernel_launch(void* const* d_in, const int* in_sizes, int n_in,
                              void* d_out, int out_size, void* d_ws,
                              size_t ws_size, hipStream_t stream) {
  const float* h    = (const float*)d_in[0];
  const float* x    = (const float*)d_in[1];
  const int*  bonds = (const int*)d_in[2];
  const float* Wm1  = (const float*)d_in[3];
  const float* bm1  = (const float*)d_in[4];
  const float* Wm2  = (const float*)d_in[5];
  const float* bm2  = (const float*)d_in[6];
  const float* Wn1  = (const float*)d_in[7];
  const float* bn1  = (const float*)d_in[8];
  const float* Wn2  = (const float*)d_in[9];
  const float* bn2  = (const float*)d_in[10];
  const float* Wc1  = (const float*)d_in[11];
  const float* bc1  = (const float*)d_in[12];
  const float* Wc2  = (const float*)d_in[13];

  float* out  = (float*)d_out;
  float* hout = out;
  float* xout = out + (size_t)NBATCH * NA * H;

  char* ws = (char*)d_ws;
  // layout (bytes): NEED = 172,559,360 < 173,080,576 proven available.
  const size_t OFF_DEG  = 0;                        // NA int = 80,000
  const size_t OFF_W1   = 163840;                   // 65,536
  const size_t OFF_W2   = OFF_W1 + 65536;           // 32,768
  const size_t OFF_WN1  = OFF_W2 + 32768;           // 65,536
  const size_t OFF_WN2  = OFF_WN1 + 65536;          // 32,768
  const size_t OFF_WC1  = OFF_WN2 + 32768;          // 32,768 (ends 393,216)
  const size_t OFF_ADJ2 = 393216;                   // NA*32 int = 2,560,000
  const size_t OFF_UPDV = 2953216;                  // (NB*8+8)*3 f32 = 5,760,096
  const size_t OFF_HB   = 8717312;                  // 160000*128 bf16 = 40,960,000
  const size_t OFF_MSG  = 49677312;                 // (NB*8+8)*128 bf16 = 122,882,048

  int*   degI = (int*)(ws + OFF_DEG);
  bf16*  W1p  = (bf16*)(ws + OFF_W1);
  bf16*  W2p  = (bf16*)(ws + OFF_W2);
  bf16*  Wn1p = (bf16*)(ws + OFF_WN1);
  bf16*  Wn2p = (bf16*)(ws + OFF_WN2);
  bf16*  Wc1p = (bf16*)(ws + OFF_WC1);
  int*   adj2 = (int*)(ws + OFF_ADJ2);
  float* updv = (float*)(ws + OFF_UPDV);
  bf16*  hb   = (bf16*)(ws + OFF_HB);
  bf16*  msgB = (bf16*)(ws + OFF_MSG);

  // zero the NULL bond's msg rows (8 x 256B) and updv slots (96B)
  (void)hipMemsetAsync(msgB + (size_t)NB * 8 * H, 0, 8 * H * sizeof(bf16),
                       stream);
  (void)hipMemsetAsync(updv + (size_t)NB * 8 * 3, 0, 8 * 3 * sizeof(float),
                       stream);

  cast_h<<<NBATCH * NA * H / 1024, 256, 0, stream>>>(h, hb);
  pack_w<<<128, 256, 0, stream>>>(Wm1, W1p, 256);
  pack_w<<<64, 256, 0, stream>>>(Wm2, W2p, 128);
  pack_w<<<128, 256, 0, stream>>>(Wn1, Wn1p, 256);
  pack_w<<<64, 256, 0, stream>>>(Wn2, Wn2p, 128);
  pack_w<<<64, 256, 0, stream>>>(Wc1, Wc1p, 128);

  init_adj<<<(NA * ADJ_CAP + 255) / 256, 256, 0, stream>>>(degI, adj2);
  build_adj2<<<(NB + 255) / 256, 256, 0, stream>>>(bonds, degI, adj2);

  msg_kernel<<<NB * NBATCH / 64, 256, 0, stream>>>(
      hb, x, bonds, W1p, bm1, W2p, bm2, Wm1 + 256 * H, Wc1p, bc1, Wc2,
      msgB, updv);
  node_kernel<<<NBATCH * NA / 32, 256, 0, stream>>>(
      h, hb, msgB, updv, degI, adj2, Wn1p, bn1, Wn2p, bn2, x,
      hout, xout);
}

// Round 9
// 452.356 us; speedup vs baseline: 1.3475x; 1.1124x over previous
//
#include <hip/hip_runtime.h>

// BondAwareEGNN fused layer — round 14.
//
// Round-13 post-mortem: msg M=32xN=64 WIN (224->174.5us, MfmaUtil 15.3);
// node null-padding REGRESSED ~+43us — unconditional 8-entry gather
// inflates volume 33% (avg deg 6 -> always 8 rows + extra updv). Volume
// beat latency. Total 510->503 masked the msg win.
//
// Round-14: node reverted to r12 conditional int4 gather; msg kept at
// r13; aux trimmed: 5x pack_w -> 1x pack_all, init_adj + null-row
// memsets dropped (13 -> 7 dispatches).

#define H      128
#define NA     20000
#define NB     60000
#define NBATCH 8
#define ADJ_CAP 32

typedef __bf16 bf16;
typedef __bf16 bf16x4 __attribute__((ext_vector_type(4)));
typedef __bf16 bf16x8 __attribute__((ext_vector_type(8)));
typedef float  f32x4  __attribute__((ext_vector_type(4)));

__device__ __forceinline__ float silu_f(float v) {
  float e = __expf(-v);
  return v * __builtin_amdgcn_rcpf(1.0f + e);  // 1-ulp rcp; inf -> 0 ok
}

// XOR-swizzled index into a [R][128] bf16 tile. Row stride 256B (bank
// neutral); 16B chunk index XOR'd with row&7 rotates banks. Bijective per
// row; 8-element chunks stay contiguous so bf16x8 loads/stores still work.
__device__ __forceinline__ int tswz(int row, int col) {
  return (row << 7) + (((((col) >> 3) ^ (row & 7)) << 3) | (col & 7));
}

__global__ void cast_h(const float* __restrict__ src, bf16* __restrict__ dst) {
  int i = blockIdx.x * 256 + threadIdx.x;  // one float4 per thread
  float4 v = *(const float4*)(src + (size_t)i * 4);
  bf16x4 t = {(bf16)v.x, (bf16)v.y, (bf16)v.z, (bf16)v.w};
  *(bf16x4*)(dst + (size_t)i * 4) = t;
}

// fp32 KxN(128) row-major -> bf16 fragment-linear (8 bf16 per lane-frag).
__device__ __forceinline__ void pack_one(const float* __restrict__ src,
                                         bf16* __restrict__ dst, int K,
                                         int i) {
  int k = i >> 7, n = i & 127;
  int nt = n >> 4, ks = k >> 5;
  int lane = (((k >> 3) & 3) << 4) | (n & 15);
  int j = k & 7;
  int KS = K >> 5;
  dst[((((nt * KS + ks) * 64) + lane) << 3) + j] = (bf16)src[i];
}

// all five weight packs in one dispatch (ranges: 32K,16K,32K,16K,16K)
__global__ void pack_all(const float* __restrict__ Wm1,
                         const float* __restrict__ Wm2,
                         const float* __restrict__ Wn1,
                         const float* __restrict__ Wn2,
                         const float* __restrict__ Wc1,
                         bf16* __restrict__ W1p, bf16* __restrict__ W2p,
                         bf16* __restrict__ Wn1p, bf16* __restrict__ Wn2p,
                         bf16* __restrict__ Wc1p) {
  int i = blockIdx.x * 256 + threadIdx.x;
  if (i < 32768)       pack_one(Wm1, W1p, 256, i);
  else if (i < 49152)  pack_one(Wm2, W2p, 128, i - 32768);
  else if (i < 81920)  pack_one(Wn1, Wn1p, 256, i - 49152);
  else if (i < 98304)  pack_one(Wn2, Wn2p, 128, i - 81920);
  else if (i < 114688) pack_one(Wc1, Wc1p, 128, i - 98304);
}

// ---------------- adjacency build (fixed-capacity slots) ----------------
__global__ void build_adj2(const int* __restrict__ bonds,
                           int* __restrict__ degI, int* __restrict__ adj2) {
  int e = blockIdx.x * 256 + threadIdx.x;
  if (e >= NB) return;
  int s = bonds[2 * e], d = bonds[2 * e + 1];
  int p = atomicAdd(&degI[s], 1);
  if (p < ADJ_CAP) adj2[s * ADJ_CAP + p] = (e << 1);        // src: sign -
  p = atomicAdd(&degI[d], 1);
  if (p < ADJ_CAP) adj2[d * ADJ_CAP + p] = (e << 1) | 1;    // dst: sign +
}

// ---------------- message kernel (M=32 x N=64 per wave) ----------------
__global__ __launch_bounds__(256, 4) void msg_kernel(
    const bf16* __restrict__ hb, const float* __restrict__ x,
    const int* __restrict__ bonds,
    const bf16* __restrict__ W1p, const float* __restrict__ bm1,
    const bf16* __restrict__ W2p, const float* __restrict__ bm2,
    const float* __restrict__ w1c,   // Wm1 row 256 (dist row), fp32[128]
    const bf16* __restrict__ Wc1p, const float* __restrict__ bc1,
    const float* __restrict__ Wc2,
    bf16* __restrict__ msgOut, float* __restrict__ updv) {
  // [64][128] swizzled tile: T after layer-1, messages after layer-2.
  __shared__ __align__(16) bf16 Tbuf[64 * 128];
  __shared__ float cds[64 * 3];
  __shared__ float dists[64];
  __shared__ float bm1s[128], bm2s[128], w1cs[128], bc1s[128], wc2s[128];
  __shared__ float cwpart[2][64];

  const int tid = threadIdx.x, blk = blockIdx.x;

  if (tid < 64) {
    int Rg = blk * 64 + tid;
    int bond = Rg >> 3, batch = Rg & 7;
    int s = bonds[2 * bond], dn = bonds[2 * bond + 1];
    const float* xs = x + (size_t)(batch * NA + s) * 3;
    const float* xd = x + (size_t)(batch * NA + dn) * 3;
    float c0 = xd[0] - xs[0], c1 = xd[1] - xs[1], c2 = xd[2] - xs[2];
    cds[tid * 3 + 0] = c0; cds[tid * 3 + 1] = c1; cds[tid * 3 + 2] = c2;
    dists[tid] = sqrtf(c0 * c0 + c1 * c1 + c2 * c2);
  }
  if (tid < 128) {
    bm1s[tid] = bm1[tid]; bm2s[tid] = bm2[tid]; w1cs[tid] = w1c[tid];
    bc1s[tid] = bc1[tid]; wc2s[tid] = Wc2[tid];
  }
  __syncthreads();

  const int lane = tid & 63;
  const int quad = lane >> 4, l16 = lane & 15;
  const int wave = tid >> 6;
  const int rowBase = (wave >> 1) * 32;    // 2 row-groups of 32
  const int colG = wave & 1;               // 2 col-groups of 64
  const int colBase = colG * 64;
  const bf16x8* W1v = (const bf16x8*)W1p;
  const bf16x8* W2v = (const bf16x8*)W2p;
  const bf16x8* Wc1v = (const bf16x8*)Wc1p;

  // per-lane A-row metadata, two row sets (rowBase+l16, rowBase+16+l16)
  const int Rg0 = blk * 64 + rowBase + l16;
  const int bn0 = Rg0 >> 3, bat0 = Rg0 & 7;
  const bf16* hs0 = hb + (size_t)(bat0 * NA + bonds[2 * bn0]) * H;
  const bf16* hd0 = hb + (size_t)(bat0 * NA + bonds[2 * bn0 + 1]) * H;
  const int Rg1 = Rg0 + 16;
  const int bn1_ = Rg1 >> 3, bat1 = Rg1 & 7;
  const bf16* hs1 = hb + (size_t)(bat1 * NA + bonds[2 * bn1_]) * H;
  const bf16* hd1 = hb + (size_t)(bat1 * NA + bonds[2 * bn1_ + 1]) * H;

  f32x4 acc0[4], acc1[4];
#pragma unroll
  for (int nt = 0; nt < 4; nt++) {
    acc0[nt] = (f32x4){0.f, 0.f, 0.f, 0.f};
    acc1[nt] = (f32x4){0.f, 0.f, 0.f, 0.f};
  }

  // ---- layer 1: K = 256; each B fragment feeds 2 MFMAs ----
#pragma unroll
  for (int ks = 0; ks < 4; ks++) {
    bf16x8 a0 = *(const bf16x8*)(hs0 + ks * 32 + quad * 8);
    bf16x8 a1 = *(const bf16x8*)(hs1 + ks * 32 + quad * 8);
#pragma unroll
    for (int nt = 0; nt < 4; nt++) {
      bf16x8 b = W1v[((colG * 4 + nt) * 8 + ks) * 64 + lane];
      acc0[nt] = __builtin_amdgcn_mfma_f32_16x16x32_bf16(a0, b, acc0[nt], 0, 0, 0);
      acc1[nt] = __builtin_amdgcn_mfma_f32_16x16x32_bf16(a1, b, acc1[nt], 0, 0, 0);
    }
  }
#pragma unroll
  for (int ks = 4; ks < 8; ks++) {
    bf16x8 a0 = *(const bf16x8*)(hd0 + (ks - 4) * 32 + quad * 8);
    bf16x8 a1 = *(const bf16x8*)(hd1 + (ks - 4) * 32 + quad * 8);
#pragma unroll
    for (int nt = 0; nt < 4; nt++) {
      bf16x8 b = W1v[((colG * 4 + nt) * 8 + ks) * 64 + lane];
      acc0[nt] = __builtin_amdgcn_mfma_f32_16x16x32_bf16(a0, b, acc0[nt], 0, 0, 0);
      acc1[nt] = __builtin_amdgcn_mfma_f32_16x16x32_bf16(a1, b, acc1[nt], 0, 0, 0);
    }
  }
  // t1 epilogue -> Tbuf
#pragma unroll
  for (int nt = 0; nt < 4; nt++) {
    int col = colBase + nt * 16 + l16;
    float bb = bm1s[col], wc = w1cs[col];
#pragma unroll
    for (int reg = 0; reg < 4; reg++) {
      int row0 = rowBase + quad * 4 + reg;
      int row1 = row0 + 16;
      Tbuf[tswz(row0, col)] = (bf16)silu_f(acc0[nt][reg] + bb + dists[row0] * wc);
      Tbuf[tswz(row1, col)] = (bf16)silu_f(acc1[nt][reg] + bb + dists[row1] * wc);
    }
  }
  __syncthreads();   // T complete

  // ---- layer 2: K = 128 -> messages ----
#pragma unroll
  for (int nt = 0; nt < 4; nt++) {
    acc0[nt] = (f32x4){0.f, 0.f, 0.f, 0.f};
    acc1[nt] = (f32x4){0.f, 0.f, 0.f, 0.f};
  }
#pragma unroll
  for (int ks = 0; ks < 4; ks++) {
    bf16x8 a0 = *(const bf16x8*)&Tbuf[tswz(rowBase + l16, ks * 32 + quad * 8)];
    bf16x8 a1 = *(const bf16x8*)&Tbuf[tswz(rowBase + 16 + l16, ks * 32 + quad * 8)];
#pragma unroll
    for (int nt = 0; nt < 4; nt++) {
      bf16x8 b = W2v[((colG * 4 + nt) * 4 + ks) * 64 + lane];
      acc0[nt] = __builtin_amdgcn_mfma_f32_16x16x32_bf16(a0, b, acc0[nt], 0, 0, 0);
      acc1[nt] = __builtin_amdgcn_mfma_f32_16x16x32_bf16(a1, b, acc1[nt], 0, 0, 0);
    }
  }
  __syncthreads();   // all T reads done; safe to overwrite
#pragma unroll
  for (int nt = 0; nt < 4; nt++) {
    int col = colBase + nt * 16 + l16;
    float bb = bm2s[col];
#pragma unroll
    for (int reg = 0; reg < 4; reg++) {
      int row0 = rowBase + quad * 4 + reg;
      int row1 = row0 + 16;
      Tbuf[tswz(row0, col)] = (bf16)silu_f(acc0[nt][reg] + bb);
      Tbuf[tswz(row1, col)] = (bf16)silu_f(acc1[nt][reg] + bb);
    }
  }
  __syncthreads();   // messages complete

  // ---- coord head ----
#pragma unroll
  for (int nt = 0; nt < 4; nt++) {
    acc0[nt] = (f32x4){0.f, 0.f, 0.f, 0.f};
    acc1[nt] = (f32x4){0.f, 0.f, 0.f, 0.f};
  }
#pragma unroll
  for (int ks = 0; ks < 4; ks++) {
    bf16x8 a0 = *(const bf16x8*)&Tbuf[tswz(rowBase + l16, ks * 32 + quad * 8)];
    bf16x8 a1 = *(const bf16x8*)&Tbuf[tswz(rowBase + 16 + l16, ks * 32 + quad * 8)];
#pragma unroll
    for (int nt = 0; nt < 4; nt++) {
      bf16x8 b = Wc1v[((colG * 4 + nt) * 4 + ks) * 64 + lane];
      acc0[nt] = __builtin_amdgcn_mfma_f32_16x16x32_bf16(a0, b, acc0[nt], 0, 0, 0);
      acc1[nt] = __builtin_amdgcn_mfma_f32_16x16x32_bf16(a1, b, acc1[nt], 0, 0, 0);
    }
  }

  // copy 64 message rows to global (4 x 16B chunks per thread, coalesced)
#pragma unroll
  for (int i = 0; i < 4; i++) {
    int item = i * 256 + tid;
    int row = item >> 4, cg = item & 15;
    *(bf16x8*)&msgOut[(size_t)(blk * 64 + row) * H + cg * 8] =
        *(const bf16x8*)&Tbuf[tswz(row, cg * 8)];
  }

  float cwp0[4] = {0.f, 0.f, 0.f, 0.f};
  float cwp1[4] = {0.f, 0.f, 0.f, 0.f};
#pragma unroll
  for (int nt = 0; nt < 4; nt++) {
    int col = colBase + nt * 16 + l16;
    float bb = bc1s[col], w2 = wc2s[col];
#pragma unroll
    for (int reg = 0; reg < 4; reg++) {
      cwp0[reg] += silu_f(acc0[nt][reg] + bb) * w2;
      cwp1[reg] += silu_f(acc1[nt][reg] + bb) * w2;
    }
  }
#pragma unroll
  for (int reg = 0; reg < 4; reg++) {
    float s0 = cwp0[reg], s1 = cwp1[reg];
    s0 += __shfl_xor(s0, 1); s1 += __shfl_xor(s1, 1);
    s0 += __shfl_xor(s0, 2); s1 += __shfl_xor(s1, 2);
    s0 += __shfl_xor(s0, 4); s1 += __shfl_xor(s1, 4);
    s0 += __shfl_xor(s0, 8); s1 += __shfl_xor(s1, 8);
    cwp0[reg] = s0; cwp1[reg] = s1;
  }
  if (l16 == 0) {
#pragma unroll
    for (int reg = 0; reg < 4; reg++) {
      int row0 = rowBase + quad * 4 + reg;
      cwpart[colG][row0] = cwp0[reg];
      cwpart[colG][row0 + 16] = cwp1[reg];
    }
  }
  __syncthreads();   // both col-halves' partials in
  if (colG == 0 && l16 == 0) {
#pragma unroll
    for (int reg = 0; reg < 4; reg++) {
#pragma unroll
      for (int rs = 0; rs < 2; rs++) {
        int row = rowBase + quad * 4 + reg + rs * 16;
        size_t Rg = (size_t)blk * 64 + row;
        float cw = cwpart[0][row] + cwpart[1][row];
        float inv = 1.0f / (dists[row] + 1e-8f);
#pragma unroll
        for (int c = 0; c < 3; c++)
          updv[Rg * 3 + c] = cds[row * 3 + c] * inv * cw;
      }
    }
  }
}

// ---------------- node kernel (2-phase; conditional int4 gather) ----------
// Phase 1: thread = (row, 32B chunk). 8 threads cover each 256B msg row;
// adj entries fetched 4-at-a-time via int4 (adj2 rows 16B-aligned).
// fp32 acc -> bf16 agg tile in LDS; x_out fused.
// Phase 2: waves = 2 row-grp x 2 col-grp, acc[4].
__global__ __launch_bounds__(256, 6) void node_kernel(
    const float* __restrict__ h, const bf16* __restrict__ hb,
    const bf16* __restrict__ msg, const float* __restrict__ updv,
    const int* __restrict__ degI, const int* __restrict__ adj2,
    const bf16* __restrict__ Wn1p, const float* __restrict__ bn1,
    const bf16* __restrict__ Wn2p, const float* __restrict__ bn2,
    const float* __restrict__ x,
    float* __restrict__ hout, float* __restrict__ xout) {
  __shared__ __align__(16) bf16 Abuf[32 * 128];
  __shared__ __align__(16) bf16 Tbuf[32 * 128];

  const int tid = threadIdx.x, blk = blockIdx.x;

  // ---- phase 1: gather ----
  {
    const int row = tid >> 3, c8 = tid & 7;       // 32 rows x 8 chunks
    const int Rg = blk * 32 + row;                // batch*NA + atom
    const int atomA = Rg % NA, batA = Rg / NA;
    int deg = degI[atomA];
    if (deg > ADJ_CAP) deg = ADJ_CAP;
    const int* ap = adj2 + atomA * ADJ_CAP;
    float a16[16];
#pragma unroll
    for (int t = 0; t < 16; t++) a16[t] = 0.f;
    float sx = 0.f, sy = 0.f, sz = 0.f;
    int j = 0;
    for (; j + 4 <= deg; j += 4) {
      int4 e4 = *(const int4*)&ap[j];   // one load, 4 entries
      const bf16* m0 = msg + ((size_t)(e4.x >> 1) * 8 + batA) * H + c8 * 16;
      const bf16* m1 = msg + ((size_t)(e4.y >> 1) * 8 + batA) * H + c8 * 16;
      const bf16* m2 = msg + ((size_t)(e4.z >> 1) * 8 + batA) * H + c8 * 16;
      const bf16* m3 = msg + ((size_t)(e4.w >> 1) * 8 + batA) * H + c8 * 16;
      bf16x8 v0 = *(const bf16x8*)(m0), v1 = *(const bf16x8*)(m0 + 8);
      bf16x8 u0 = *(const bf16x8*)(m1), u1 = *(const bf16x8*)(m1 + 8);
      bf16x8 p0 = *(const bf16x8*)(m2), p1 = *(const bf16x8*)(m2 + 8);
      bf16x8 q0 = *(const bf16x8*)(m3), q1 = *(const bf16x8*)(m3 + 8);
      if (c8 == 0) {
        float sg0 = (e4.x & 1) ? 1.0f : -1.0f;
        float sg1 = (e4.y & 1) ? 1.0f : -1.0f;
        float sg2 = (e4.z & 1) ? 1.0f : -1.0f;
        float sg3 = (e4.w & 1) ? 1.0f : -1.0f;
        const float* uv0 = updv + ((size_t)(e4.x >> 1) * 8 + batA) * 3;
        const float* uv1 = updv + ((size_t)(e4.y >> 1) * 8 + batA) * 3;
        const float* uv2 = updv + ((size_t)(e4.z >> 1) * 8 + batA) * 3;
        const float* uv3 = updv + ((size_t)(e4.w >> 1) * 8 + batA) * 3;
        sx += sg0 * uv0[0] + sg1 * uv1[0] + sg2 * uv2[0] + sg3 * uv3[0];
        sy += sg0 * uv0[1] + sg1 * uv1[1] + sg2 * uv2[1] + sg3 * uv3[1];
        sz += sg0 * uv0[2] + sg1 * uv1[2] + sg2 * uv2[2] + sg3 * uv3[2];
      }
#pragma unroll
      for (int t = 0; t < 8; t++) {
        a16[t]     += ((float)v0[t] + (float)u0[t]) + ((float)p0[t] + (float)q0[t]);
        a16[8 + t] += ((float)v1[t] + (float)u1[t]) + ((float)p1[t] + (float)q1[t]);
      }
    }
    for (; j < deg; j++) {
      int ent0 = ap[j];
      const bf16* m0 = msg + ((size_t)(ent0 >> 1) * 8 + batA) * H + c8 * 16;
      bf16x8 v0 = *(const bf16x8*)(m0);
      bf16x8 v1 = *(const bf16x8*)(m0 + 8);
      if (c8 == 0) {
        float sg0 = (ent0 & 1) ? 1.0f : -1.0f;
        const float* uv0 = updv + ((size_t)(ent0 >> 1) * 8 + batA) * 3;
        sx += sg0 * uv0[0]; sy += sg0 * uv0[1]; sz += sg0 * uv0[2];
      }
#pragma unroll
      for (int t = 0; t < 8; t++) {
        a16[t]     += (float)v0[t];
        a16[8 + t] += (float)v1[t];
      }
    }
    if (c8 == 0) {   // x finalize
      float cnt = deg < 1 ? 1.0f : (float)deg;
      float inv = 1.0f / cnt;
      size_t o = (size_t)Rg * 3;
      xout[o + 0] = x[o + 0] + sx * inv;
      xout[o + 1] = x[o + 1] + sy * inv;
      xout[o + 2] = x[o + 2] + sz * inv;
    }
    bf16x8 w0, w1;
#pragma unroll
    for (int t = 0; t < 8; t++) { w0[t] = (bf16)a16[t]; w1[t] = (bf16)a16[8 + t]; }
    *(bf16x8*)&Abuf[tswz(row, c8 * 16)]     = w0;
    *(bf16x8*)&Abuf[tswz(row, c8 * 16 + 8)] = w1;
  }
  __syncthreads();   // agg tile ready

  // ---- phase 2: node MLP, N-split ----
  const int lane = tid & 63, wave = tid >> 6;
  const int quad = lane >> 4, l16 = lane & 15;
  const int rowG = (wave >> 1) * 16, colG = wave & 1, colBase = colG * 64;
  const int RgA = blk * 32 + rowG + l16;
  const bf16* hrow = hb + (size_t)RgA * H;
  const bf16x8* W1v = (const bf16x8*)Wn1p;
  const bf16x8* W2v = (const bf16x8*)Wn2p;

  f32x4 acc[4];
#pragma unroll
  for (int nt = 0; nt < 4; nt++) acc[nt] = (f32x4){0.f, 0.f, 0.f, 0.f};

  // layer-1 first half: h (bf16) register-direct from global
#pragma unroll
  for (int ks = 0; ks < 4; ks++) {
    bf16x8 a = *(const bf16x8*)(hrow + ks * 32 + quad * 8);
#pragma unroll
    for (int nt = 0; nt < 4; nt++) {
      bf16x8 b = W1v[((colG * 4 + nt) * 8 + ks) * 64 + lane];
      acc[nt] = __builtin_amdgcn_mfma_f32_16x16x32_bf16(a, b, acc[nt], 0, 0, 0);
    }
  }
  // layer-1 second half: aggregated from LDS
#pragma unroll
  for (int ks2 = 0; ks2 < 4; ks2++) {
    bf16x8 a = *(const bf16x8*)&Abuf[tswz(rowG + l16, ks2 * 32 + quad * 8)];
#pragma unroll
    for (int nt = 0; nt < 4; nt++) {
      bf16x8 b = W1v[((colG * 4 + nt) * 8 + 4 + ks2) * 64 + lane];
      acc[nt] = __builtin_amdgcn_mfma_f32_16x16x32_bf16(a, b, acc[nt], 0, 0, 0);
    }
  }
#pragma unroll
  for (int nt = 0; nt < 4; nt++) {
    int col = colBase + nt * 16 + l16;
    float bb = bn1[col];
#pragma unroll
    for (int reg = 0; reg < 4; reg++) {
      int row = rowG + quad * 4 + reg;
      Tbuf[tswz(row, col)] = (bf16)silu_f(acc[nt][reg] + bb);
    }
  }
  __syncthreads();   // T complete (both col halves)

#pragma unroll
  for (int nt = 0; nt < 4; nt++) acc[nt] = (f32x4){0.f, 0.f, 0.f, 0.f};
#pragma unroll
  for (int ks = 0; ks < 4; ks++) {
    bf16x8 a = *(const bf16x8*)&Tbuf[tswz(rowG + l16, ks * 32 + quad * 8)];
#pragma unroll
    for (int nt = 0; nt < 4; nt++) {
      bf16x8 b = W2v[((colG * 4 + nt) * 4 + ks) * 64 + lane];
      acc[nt] = __builtin_amdgcn_mfma_f32_16x16x32_bf16(a, b, acc[nt], 0, 0, 0);
    }
  }
#pragma unroll
  for (int nt = 0; nt < 4; nt++) {
    int col = colBase + nt * 16 + l16;
    float bb = bn2[col];
#pragma unroll
    for (int reg = 0; reg < 4; reg++) {
      size_t Ro = (size_t)blk * 32 + rowG + quad * 4 + reg;
      hout[Ro * H + col] = h[Ro * H + col] + acc[nt][reg] + bb;
    }
  }
}

extern "C" void kernel_launch(void* const* d_in, const int* in_sizes, int n_in,
                              void* d_out, int out_size, void* d_ws,
                              size_t ws_size, hipStream_t stream) {
  const float* h    = (const float*)d_in[0];
  const float* x    = (const float*)d_in[1];
  const int*  bonds = (const int*)d_in[2];
  const float* Wm1  = (const float*)d_in[3];
  const float* bm1  = (const float*)d_in[4];
  const float* Wm2  = (const float*)d_in[5];
  const float* bm2  = (const float*)d_in[6];
  const float* Wn1  = (const float*)d_in[7];
  const float* bn1  = (const float*)d_in[8];
  const float* Wn2  = (const float*)d_in[9];
  const float* bn2  = (const float*)d_in[10];
  const float* Wc1  = (const float*)d_in[11];
  const float* bc1  = (const float*)d_in[12];
  const float* Wc2  = (const float*)d_in[13];

  float* out  = (float*)d_out;
  float* hout = out;
  float* xout = out + (size_t)NBATCH * NA * H;

  char* ws = (char*)d_ws;
  // layout (bytes): NEED = 172,553,216 < 173,080,576 proven available.
  const size_t OFF_DEG  = 0;                        // NA int = 80,000
  const size_t OFF_W1   = 163840;                   // 65,536
  const size_t OFF_W2   = OFF_W1 + 65536;           // 32,768
  const size_t OFF_WN1  = OFF_W2 + 32768;           // 65,536
  const size_t OFF_WN2  = OFF_WN1 + 65536;          // 32,768
  const size_t OFF_WC1  = OFF_WN2 + 32768;          // 32,768 (ends 393,216)
  const size_t OFF_ADJ2 = 393216;                   // NA*32 int = 2,560,000
  const size_t OFF_UPDV = 2953216;                  // NB*8*3 f32 = 5,760,000
  const size_t OFF_HB   = 8713216;                  // 160000*128 bf16 = 40,960,000
  const size_t OFF_MSG  = 49673216;                 // NB*8*128 bf16 = 122,880,000

  int*   degI = (int*)(ws + OFF_DEG);
  bf16*  W1p  = (bf16*)(ws + OFF_W1);
  bf16*  W2p  = (bf16*)(ws + OFF_W2);
  bf16*  Wn1p = (bf16*)(ws + OFF_WN1);
  bf16*  Wn2p = (bf16*)(ws + OFF_WN2);
  bf16*  Wc1p = (bf16*)(ws + OFF_WC1);
  int*   adj2 = (int*)(ws + OFF_ADJ2);
  float* updv = (float*)(ws + OFF_UPDV);
  bf16*  hb   = (bf16*)(ws + OFF_HB);
  bf16*  msgB = (bf16*)(ws + OFF_MSG);

  (void)hipMemsetAsync(degI, 0, NA * sizeof(int), stream);

  cast_h<<<NBATCH * NA * H / 1024, 256, 0, stream>>>(h, hb);
  pack_all<<<448, 256, 0, stream>>>(Wm1, Wm2, Wn1, Wn2, Wc1,
                                    W1p, W2p, Wn1p, Wn2p, Wc1p);
  build_adj2<<<(NB + 255) / 256, 256, 0, stream>>>(bonds, degI, adj2);

  msg_kernel<<<NB * NBATCH / 64, 256, 0, stream>>>(
      hb, x, bonds, W1p, bm1, W2p, bm2, Wm1 + 256 * H, Wc1p, bc1, Wc2,
      msgB, updv);
  node_kernel<<<NBATCH * NA / 32, 256, 0, stream>>>(
      h, hb, msgB, updv, degI, adj2, Wn1p, bn1, Wn2p, bn2, x,
      hout, xout);
}

// Round 10
// 447.016 us; speedup vs baseline: 1.3636x; 1.0119x over previous
//
#include <hip/hip_runtime.h>

// BondAwareEGNN fused layer — round 15.
//
// Round-14 post-mortem: matched (503->452). msg: MfmaUtil 15.5, VALU 41.5
// — VALU issues 2.7x MFMA cycles. Cause: C-layout puts a lane's 4 acc
// values in 4 DIFFERENT rows -> per-element 2B LDS epilogue writes, each
// with its own tswz arith + per-reg dists lookups + 4-level shfl reduce.
//
// Round-15: OPERAND SWAP — mfma(W_frag, h_frag) gives T^T in registers:
// lane l16 = bond-row (fixed), regs = 4 CONSECUTIVE cols. Epilogues become
// one bf16x4 8B LDS write per tile; dist hoisted per-lane; bias via f32x4;
// coord-head reduce = 2 shfl_xor; node hout = float4 read+store. Applied
// to all 3 msg GEMMs + both node GEMMs. Pure instruction-count change:
// FETCH/WRITE must stay ~158/140MB.

#define H      128
#define NA     20000
#define NB     60000
#define NBATCH 8
#define ADJ_CAP 32

typedef __bf16 bf16;
typedef __bf16 bf16x4 __attribute__((ext_vector_type(4)));
typedef __bf16 bf16x8 __attribute__((ext_vector_type(8)));
typedef float  f32x4  __attribute__((ext_vector_type(4)));

__device__ __forceinline__ float silu_f(float v) {
  float e = __expf(-v);
  return v * __builtin_amdgcn_rcpf(1.0f + e);  // 1-ulp rcp; inf -> 0 ok
}

// XOR-swizzled index into a [R][128] bf16 tile. Row stride 256B (bank
// neutral); 16B chunk index XOR'd with row&7 rotates banks. Bijective per
// row; 8-element chunks stay contiguous so bf16x8/bf16x4 ops still work.
__device__ __forceinline__ int tswz(int row, int col) {
  return (row << 7) + (((((col) >> 3) ^ (row & 7)) << 3) | (col & 7));
}

__global__ void cast_h(const float* __restrict__ src, bf16* __restrict__ dst) {
  int i = blockIdx.x * 256 + threadIdx.x;  // one float4 per thread
  float4 v = *(const float4*)(src + (size_t)i * 4);
  bf16x4 t = {(bf16)v.x, (bf16)v.y, (bf16)v.z, (bf16)v.w};
  *(bf16x4*)(dst + (size_t)i * 4) = t;
}

// fp32 KxN(128) row-major -> bf16 fragment-linear (8 bf16 per lane-frag).
__device__ __forceinline__ void pack_one(const float* __restrict__ src,
                                         bf16* __restrict__ dst, int K,
                                         int i) {
  int k = i >> 7, n = i & 127;
  int nt = n >> 4, ks = k >> 5;
  int lane = (((k >> 3) & 3) << 4) | (n & 15);
  int j = k & 7;
  int KS = K >> 5;
  dst[((((nt * KS + ks) * 64) + lane) << 3) + j] = (bf16)src[i];
}

// all five weight packs in one dispatch (ranges: 32K,16K,32K,16K,16K)
__global__ void pack_all(const float* __restrict__ Wm1,
                         const float* __restrict__ Wm2,
                         const float* __restrict__ Wn1,
                         const float* __restrict__ Wn2,
                         const float* __restrict__ Wc1,
                         bf16* __restrict__ W1p, bf16* __restrict__ W2p,
                         bf16* __restrict__ Wn1p, bf16* __restrict__ Wn2p,
                         bf16* __restrict__ Wc1p) {
  int i = blockIdx.x * 256 + threadIdx.x;
  if (i < 32768)       pack_one(Wm1, W1p, 256, i);
  else if (i < 49152)  pack_one(Wm2, W2p, 128, i - 32768);
  else if (i < 81920)  pack_one(Wn1, Wn1p, 256, i - 49152);
  else if (i < 98304)  pack_one(Wn2, Wn2p, 128, i - 81920);
  else if (i < 114688) pack_one(Wc1, Wc1p, 128, i - 98304);
}

// ---------------- adjacency build (fixed-capacity slots) ----------------
__global__ void build_adj2(const int* __restrict__ bonds,
                           int* __restrict__ degI, int* __restrict__ adj2) {
  int e = blockIdx.x * 256 + threadIdx.x;
  if (e >= NB) return;
  int s = bonds[2 * e], d = bonds[2 * e + 1];
  int p = atomicAdd(&degI[s], 1);
  if (p < ADJ_CAP) adj2[s * ADJ_CAP + p] = (e << 1);        // src: sign -
  p = atomicAdd(&degI[d], 1);
  if (p < ADJ_CAP) adj2[d * ADJ_CAP + p] = (e << 1) | 1;    // dst: sign +
}

// ---------------- message kernel (M=32 x N=64 per wave, swapped MFMA) ----
__global__ __launch_bounds__(256, 4) void msg_kernel(
    const bf16* __restrict__ hb, const float* __restrict__ x,
    const int* __restrict__ bonds,
    const bf16* __restrict__ W1p, const float* __restrict__ bm1,
    const bf16* __restrict__ W2p, const float* __restrict__ bm2,
    const float* __restrict__ w1c,   // Wm1 row 256 (dist row), fp32[128]
    const bf16* __restrict__ Wc1p, const float* __restrict__ bc1,
    const float* __restrict__ Wc2,
    bf16* __restrict__ msgOut, float* __restrict__ updv) {
  // [64][128] swizzled tile: T after layer-1, messages after layer-2.
  __shared__ __align__(16) bf16 Tbuf[64 * 128];
  __shared__ __align__(16) float cds[64 * 3];
  __shared__ __align__(16) float dists[64];
  __shared__ __align__(16) float bm1s[128], bm2s[128], w1cs[128];
  __shared__ __align__(16) float bc1s[128], wc2s[128];
  __shared__ float cwpart[2][64];

  const int tid = threadIdx.x, blk = blockIdx.x;

  if (tid < 64) {
    int Rg = blk * 64 + tid;
    int bond = Rg >> 3, batch = Rg & 7;
    int s = bonds[2 * bond], dn = bonds[2 * bond + 1];
    const float* xs = x + (size_t)(batch * NA + s) * 3;
    const float* xd = x + (size_t)(batch * NA + dn) * 3;
    float c0 = xd[0] - xs[0], c1 = xd[1] - xs[1], c2 = xd[2] - xs[2];
    cds[tid * 3 + 0] = c0; cds[tid * 3 + 1] = c1; cds[tid * 3 + 2] = c2;
    dists[tid] = sqrtf(c0 * c0 + c1 * c1 + c2 * c2);
  }
  if (tid < 128) {
    bm1s[tid] = bm1[tid]; bm2s[tid] = bm2[tid]; w1cs[tid] = w1c[tid];
    bc1s[tid] = bc1[tid]; wc2s[tid] = Wc2[tid];
  }
  __syncthreads();

  const int lane = tid & 63;
  const int quad = lane >> 4, l16 = lane & 15;
  const int wave = tid >> 6;
  const int rowBase = (wave >> 1) * 32;    // 2 row-groups of 32
  const int colG = wave & 1;               // 2 col-groups of 64
  const int colBase = colG * 64;
  const bf16x8* W1v = (const bf16x8*)W1p;
  const bf16x8* W2v = (const bf16x8*)W2p;
  const bf16x8* Wc1v = (const bf16x8*)Wc1p;

  // per-lane A-row metadata, two row sets (rowBase+l16, rowBase+16+l16)
  const int row0 = rowBase + l16, row1 = row0 + 16;
  const int Rg0 = blk * 64 + row0;
  const int bn0 = Rg0 >> 3, bat0 = Rg0 & 7;
  const bf16* hs0 = hb + (size_t)(bat0 * NA + bonds[2 * bn0]) * H;
  const bf16* hd0 = hb + (size_t)(bat0 * NA + bonds[2 * bn0 + 1]) * H;
  const int Rg1 = Rg0 + 16;
  const int bn1_ = Rg1 >> 3, bat1 = Rg1 & 7;
  const bf16* hs1 = hb + (size_t)(bat1 * NA + bonds[2 * bn1_]) * H;
  const bf16* hd1 = hb + (size_t)(bat1 * NA + bonds[2 * bn1_ + 1]) * H;
  const float dist0 = dists[row0], dist1 = dists[row1];

  f32x4 acc0[4], acc1[4];
#pragma unroll
  for (int nt = 0; nt < 4; nt++) {
    acc0[nt] = (f32x4){0.f, 0.f, 0.f, 0.f};
    acc1[nt] = (f32x4){0.f, 0.f, 0.f, 0.f};
  }

  // ---- layer 1: K = 256; swapped operands -> regs = 4 consecutive cols --
#pragma unroll
  for (int ks = 0; ks < 4; ks++) {
    bf16x8 a0 = *(const bf16x8*)(hs0 + ks * 32 + quad * 8);
    bf16x8 a1 = *(const bf16x8*)(hs1 + ks * 32 + quad * 8);
#pragma unroll
    for (int nt = 0; nt < 4; nt++) {
      bf16x8 b = W1v[((colG * 4 + nt) * 8 + ks) * 64 + lane];
      acc0[nt] = __builtin_amdgcn_mfma_f32_16x16x32_bf16(b, a0, acc0[nt], 0, 0, 0);
      acc1[nt] = __builtin_amdgcn_mfma_f32_16x16x32_bf16(b, a1, acc1[nt], 0, 0, 0);
    }
  }
#pragma unroll
  for (int ks = 4; ks < 8; ks++) {
    bf16x8 a0 = *(const bf16x8*)(hd0 + (ks - 4) * 32 + quad * 8);
    bf16x8 a1 = *(const bf16x8*)(hd1 + (ks - 4) * 32 + quad * 8);
#pragma unroll
    for (int nt = 0; nt < 4; nt++) {
      bf16x8 b = W1v[((colG * 4 + nt) * 8 + ks) * 64 + lane];
      acc0[nt] = __builtin_amdgcn_mfma_f32_16x16x32_bf16(b, a0, acc0[nt], 0, 0, 0);
      acc1[nt] = __builtin_amdgcn_mfma_f32_16x16x32_bf16(b, a1, acc1[nt], 0, 0, 0);
    }
  }
  // t1 epilogue -> Tbuf: one bf16x4 8B write per tile per row-set
#pragma unroll
  for (int nt = 0; nt < 4; nt++) {
    int col = colBase + nt * 16 + quad * 4;
    f32x4 bb = *(const f32x4*)&bm1s[col];
    f32x4 wc = *(const f32x4*)&w1cs[col];
    bf16x4 o0, o1;
#pragma unroll
    for (int reg = 0; reg < 4; reg++) {
      o0[reg] = (bf16)silu_f(acc0[nt][reg] + bb[reg] + dist0 * wc[reg]);
      o1[reg] = (bf16)silu_f(acc1[nt][reg] + bb[reg] + dist1 * wc[reg]);
    }
    *(bf16x4*)&Tbuf[tswz(row0, col)] = o0;
    *(bf16x4*)&Tbuf[tswz(row1, col)] = o1;
  }
  __syncthreads();   // T complete

  // ---- layer 2: K = 128 -> messages ----
#pragma unroll
  for (int nt = 0; nt < 4; nt++) {
    acc0[nt] = (f32x4){0.f, 0.f, 0.f, 0.f};
    acc1[nt] = (f32x4){0.f, 0.f, 0.f, 0.f};
  }
#pragma unroll
  for (int ks = 0; ks < 4; ks++) {
    bf16x8 a0 = *(const bf16x8*)&Tbuf[tswz(row0, ks * 32 + quad * 8)];
    bf16x8 a1 = *(const bf16x8*)&Tbuf[tswz(row1, ks * 32 + quad * 8)];
#pragma unroll
    for (int nt = 0; nt < 4; nt++) {
      bf16x8 b = W2v[((colG * 4 + nt) * 4 + ks) * 64 + lane];
      acc0[nt] = __builtin_amdgcn_mfma_f32_16x16x32_bf16(b, a0, acc0[nt], 0, 0, 0);
      acc1[nt] = __builtin_amdgcn_mfma_f32_16x16x32_bf16(b, a1, acc1[nt], 0, 0, 0);
    }
  }
  __syncthreads();   // all T reads done; safe to overwrite
#pragma unroll
  for (int nt = 0; nt < 4; nt++) {
    int col = colBase + nt * 16 + quad * 4;
    f32x4 bb = *(const f32x4*)&bm2s[col];
    bf16x4 o0, o1;
#pragma unroll
    for (int reg = 0; reg < 4; reg++) {
      o0[reg] = (bf16)silu_f(acc0[nt][reg] + bb[reg]);
      o1[reg] = (bf16)silu_f(acc1[nt][reg] + bb[reg]);
    }
    *(bf16x4*)&Tbuf[tswz(row0, col)] = o0;
    *(bf16x4*)&Tbuf[tswz(row1, col)] = o1;
  }
  __syncthreads();   // messages complete

  // ---- coord head ----
#pragma unroll
  for (int nt = 0; nt < 4; nt++) {
    acc0[nt] = (f32x4){0.f, 0.f, 0.f, 0.f};
    acc1[nt] = (f32x4){0.f, 0.f, 0.f, 0.f};
  }
#pragma unroll
  for (int ks = 0; ks < 4; ks++) {
    bf16x8 a0 = *(const bf16x8*)&Tbuf[tswz(row0, ks * 32 + quad * 8)];
    bf16x8 a1 = *(const bf16x8*)&Tbuf[tswz(row1, ks * 32 + quad * 8)];
#pragma unroll
    for (int nt = 0; nt < 4; nt++) {
      bf16x8 b = Wc1v[((colG * 4 + nt) * 4 + ks) * 64 + lane];
      acc0[nt] = __builtin_amdgcn_mfma_f32_16x16x32_bf16(b, a0, acc0[nt], 0, 0, 0);
      acc1[nt] = __builtin_amdgcn_mfma_f32_16x16x32_bf16(b, a1, acc1[nt], 0, 0, 0);
    }
  }

  // copy 64 message rows to global (4 x 16B chunks per thread, coalesced)
#pragma unroll
  for (int i = 0; i < 4; i++) {
    int item = i * 256 + tid;
    int row = item >> 4, cg = item & 15;
    *(bf16x8*)&msgOut[(size_t)(blk * 64 + row) * H + cg * 8] =
        *(const bf16x8*)&Tbuf[tswz(row, cg * 8)];
  }

  // lane-local sum over this lane's 16 cols, then reduce across quads
  float s0 = 0.f, s1 = 0.f;
#pragma unroll
  for (int nt = 0; nt < 4; nt++) {
    int col = colBase + nt * 16 + quad * 4;
    f32x4 bb = *(const f32x4*)&bc1s[col];
    f32x4 w2 = *(const f32x4*)&wc2s[col];
#pragma unroll
    for (int reg = 0; reg < 4; reg++) {
      s0 += silu_f(acc0[nt][reg] + bb[reg]) * w2[reg];
      s1 += silu_f(acc1[nt][reg] + bb[reg]) * w2[reg];
    }
  }
  s0 += __shfl_xor(s0, 16); s0 += __shfl_xor(s0, 32);
  s1 += __shfl_xor(s1, 16); s1 += __shfl_xor(s1, 32);
  if (quad == 0) {
    cwpart[colG][row0] = s0;
    cwpart[colG][row1] = s1;
  }
  __syncthreads();   // both col-halves' partials in
  if (colG == 0 && quad == 0) {
#pragma unroll
    for (int rs = 0; rs < 2; rs++) {
      int row = rs ? row1 : row0;
      size_t Rg = (size_t)blk * 64 + row;
      float cw = cwpart[0][row] + cwpart[1][row];
      float inv = 1.0f / (dists[row] + 1e-8f);
#pragma unroll
      for (int c = 0; c < 3; c++)
        updv[Rg * 3 + c] = cds[row * 3 + c] * inv * cw;
    }
  }
}

// ---------------- node kernel (2-phase; swapped MFMA phase 2) -------------
__global__ __launch_bounds__(256, 6) void node_kernel(
    const float* __restrict__ h, const bf16* __restrict__ hb,
    const bf16* __restrict__ msg, const float* __restrict__ updv,
    const int* __restrict__ degI, const int* __restrict__ adj2,
    const bf16* __restrict__ Wn1p, const float* __restrict__ bn1,
    const bf16* __restrict__ Wn2p, const float* __restrict__ bn2,
    const float* __restrict__ x,
    float* __restrict__ hout, float* __restrict__ xout) {
  __shared__ __align__(16) bf16 Abuf[32 * 128];
  __shared__ __align__(16) bf16 Tbuf[32 * 128];

  const int tid = threadIdx.x, blk = blockIdx.x;

  // ---- phase 1: gather ----
  {
    const int row = tid >> 3, c8 = tid & 7;       // 32 rows x 8 chunks
    const int Rg = blk * 32 + row;                // batch*NA + atom
    const int atomA = Rg % NA, batA = Rg / NA;
    int deg = degI[atomA];
    if (deg > ADJ_CAP) deg = ADJ_CAP;
    const int* ap = adj2 + atomA * ADJ_CAP;
    float a16[16];
#pragma unroll
    for (int t = 0; t < 16; t++) a16[t] = 0.f;
    float sx = 0.f, sy = 0.f, sz = 0.f;
    int j = 0;
    for (; j + 4 <= deg; j += 4) {
      int4 e4 = *(const int4*)&ap[j];   // one load, 4 entries
      const bf16* m0 = msg + ((size_t)(e4.x >> 1) * 8 + batA) * H + c8 * 16;
      const bf16* m1 = msg + ((size_t)(e4.y >> 1) * 8 + batA) * H + c8 * 16;
      const bf16* m2 = msg + ((size_t)(e4.z >> 1) * 8 + batA) * H + c8 * 16;
      const bf16* m3 = msg + ((size_t)(e4.w >> 1) * 8 + batA) * H + c8 * 16;
      bf16x8 v0 = *(const bf16x8*)(m0), v1 = *(const bf16x8*)(m0 + 8);
      bf16x8 u0 = *(const bf16x8*)(m1), u1 = *(const bf16x8*)(m1 + 8);
      bf16x8 p0 = *(const bf16x8*)(m2), p1 = *(const bf16x8*)(m2 + 8);
      bf16x8 q0 = *(const bf16x8*)(m3), q1 = *(const bf16x8*)(m3 + 8);
      if (c8 == 0) {
        float sg0 = (e4.x & 1) ? 1.0f : -1.0f;
        float sg1 = (e4.y & 1) ? 1.0f : -1.0f;
        float sg2 = (e4.z & 1) ? 1.0f : -1.0f;
        float sg3 = (e4.w & 1) ? 1.0f : -1.0f;
        const float* uv0 = updv + ((size_t)(e4.x >> 1) * 8 + batA) * 3;
        const float* uv1 = updv + ((size_t)(e4.y >> 1) * 8 + batA) * 3;
        const float* uv2 = updv + ((size_t)(e4.z >> 1) * 8 + batA) * 3;
        const float* uv3 = updv + ((size_t)(e4.w >> 1) * 8 + batA) * 3;
        sx += sg0 * uv0[0] + sg1 * uv1[0] + sg2 * uv2[0] + sg3 * uv3[0];
        sy += sg0 * uv0[1] + sg1 * uv1[1] + sg2 * uv2[1] + sg3 * uv3[1];
        sz += sg0 * uv0[2] + sg1 * uv1[2] + sg2 * uv2[2] + sg3 * uv3[2];
      }
#pragma unroll
      for (int t = 0; t < 8; t++) {
        a16[t]     += ((float)v0[t] + (float)u0[t]) + ((float)p0[t] + (float)q0[t]);
        a16[8 + t] += ((float)v1[t] + (float)u1[t]) + ((float)p1[t] + (float)q1[t]);
      }
    }
    for (; j < deg; j++) {
      int ent0 = ap[j];
      const bf16* m0 = msg + ((size_t)(ent0 >> 1) * 8 + batA) * H + c8 * 16;
      bf16x8 v0 = *(const bf16x8*)(m0);
      bf16x8 v1 = *(const bf16x8*)(m0 + 8);
      if (c8 == 0) {
        float sg0 = (ent0 & 1) ? 1.0f : -1.0f;
        const float* uv0 = updv + ((size_t)(ent0 >> 1) * 8 + batA) * 3;
        sx += sg0 * uv0[0]; sy += sg0 * uv0[1]; sz += sg0 * uv0[2];
      }
#pragma unroll
      for (int t = 0; t < 8; t++) {
        a16[t]     += (float)v0[t];
        a16[8 + t] += (float)v1[t];
      }
    }
    if (c8 == 0) {   // x finalize
      float cnt = deg < 1 ? 1.0f : (float)deg;
      float inv = 1.0f / cnt;
      size_t o = (size_t)Rg * 3;
      xout[o + 0] = x[o + 0] + sx * inv;
      xout[o + 1] = x[o + 1] + sy * inv;
      xout[o + 2] = x[o + 2] + sz * inv;
    }
    bf16x8 w0, w1;
#pragma unroll
    for (int t = 0; t < 8; t++) { w0[t] = (bf16)a16[t]; w1[t] = (bf16)a16[8 + t]; }
    *(bf16x8*)&Abuf[tswz(row, c8 * 16)]     = w0;
    *(bf16x8*)&Abuf[tswz(row, c8 * 16 + 8)] = w1;
  }
  __syncthreads();   // agg tile ready

  // ---- phase 2: node MLP, N-split, swapped MFMA ----
  const int lane = tid & 63, wave = tid >> 6;
  const int quad = lane >> 4, l16 = lane & 15;
  const int rowG = (wave >> 1) * 16, colG = wave & 1, colBase = colG * 64;
  const int rowL = rowG + l16;
  const size_t RgA = (size_t)blk * 32 + rowL;
  const bf16* hrow = hb + RgA * H;
  const bf16x8* W1v = (const bf16x8*)Wn1p;
  const bf16x8* W2v = (const bf16x8*)Wn2p;

  f32x4 acc[4];
#pragma unroll
  for (int nt = 0; nt < 4; nt++) acc[nt] = (f32x4){0.f, 0.f, 0.f, 0.f};

  // layer-1 first half: h (bf16) register-direct from global
#pragma unroll
  for (int ks = 0; ks < 4; ks++) {
    bf16x8 a = *(const bf16x8*)(hrow + ks * 32 + quad * 8);
#pragma unroll
    for (int nt = 0; nt < 4; nt++) {
      bf16x8 b = W1v[((colG * 4 + nt) * 8 + ks) * 64 + lane];
      acc[nt] = __builtin_amdgcn_mfma_f32_16x16x32_bf16(b, a, acc[nt], 0, 0, 0);
    }
  }
  // layer-1 second half: aggregated from LDS
#pragma unroll
  for (int ks2 = 0; ks2 < 4; ks2++) {
    bf16x8 a = *(const bf16x8*)&Abuf[tswz(rowL, ks2 * 32 + quad * 8)];
#pragma unroll
    for (int nt = 0; nt < 4; nt++) {
      bf16x8 b = W1v[((colG * 4 + nt) * 8 + 4 + ks2) * 64 + lane];
      acc[nt] = __builtin_amdgcn_mfma_f32_16x16x32_bf16(b, a, acc[nt], 0, 0, 0);
    }
  }
#pragma unroll
  for (int nt = 0; nt < 4; nt++) {
    int col = colBase + nt * 16 + quad * 4;
    f32x4 bb = *(const f32x4*)&bn1[col];
    bf16x4 o;
#pragma unroll
    for (int reg = 0; reg < 4; reg++)
      o[reg] = (bf16)silu_f(acc[nt][reg] + bb[reg]);
    *(bf16x4*)&Tbuf[tswz(rowL, col)] = o;
  }
  __syncthreads();   // T complete (both col halves)

#pragma unroll
  for (int nt = 0; nt < 4; nt++) acc[nt] = (f32x4){0.f, 0.f, 0.f, 0.f};
#pragma unroll
  for (int ks = 0; ks < 4; ks++) {
    bf16x8 a = *(const bf16x8*)&Tbuf[tswz(rowL, ks * 32 + quad * 8)];
#pragma unroll
    for (int nt = 0; nt < 4; nt++) {
      bf16x8 b = W2v[((colG * 4 + nt) * 4 + ks) * 64 + lane];
      acc[nt] = __builtin_amdgcn_mfma_f32_16x16x32_bf16(b, a, acc[nt], 0, 0, 0);
    }
  }
#pragma unroll
  for (int nt = 0; nt < 4; nt++) {
    int col = colBase + nt * 16 + quad * 4;
    f32x4 bb = *(const f32x4*)&bn2[col];
    f32x4 hv = *(const f32x4*)&h[RgA * H + col];
    f32x4 o;
#pragma unroll
    for (int reg = 0; reg < 4; reg++)
      o[reg] = hv[reg] + acc[nt][reg] + bb[reg];
    *(f32x4*)&hout[RgA * H + col] = o;
  }
}

extern "C" void kernel_launch(void* const* d_in, const int* in_sizes, int n_in,
                              void* d_out, int out_size, void* d_ws,
                              size_t ws_size, hipStream_t stream) {
  const float* h    = (const float*)d_in[0];
  const float* x    = (const float*)d_in[1];
  const int*  bonds = (const int*)d_in[2];
  const float* Wm1  = (const float*)d_in[3];
  const float* bm1  = (const float*)d_in[4];
  const float* Wm2  = (const float*)d_in[5];
  const float* bm2  = (const float*)d_in[6];
  const float* Wn1  = (const float*)d_in[7];
  const float* bn1  = (const float*)d_in[8];
  const float* Wn2  = (const float*)d_in[9];
  const float* bn2  = (const float*)d_in[10];
  const float* Wc1  = (const float*)d_in[11];
  const float* bc1  = (const float*)d_in[12];
  const float* Wc2  = (const float*)d_in[13];

  float* out  = (float*)d_out;
  float* hout = out;
  float* xout = out + (size_t)NBATCH * NA * H;

  char* ws = (char*)d_ws;
  // layout (bytes): NEED = 172,553,216 < 173,080,576 proven available.
  const size_t OFF_DEG  = 0;                        // NA int = 80,000
  const size_t OFF_W1   = 163840;                   // 65,536
  const size_t OFF_W2   = OFF_W1 + 65536;           // 32,768
  const size_t OFF_WN1  = OFF_W2 + 32768;           // 65,536
  const size_t OFF_WN2  = OFF_WN1 + 65536;          // 32,768
  const size_t OFF_WC1  = OFF_WN2 + 32768;          // 32,768 (ends 393,216)
  const size_t OFF_ADJ2 = 393216;                   // NA*32 int = 2,560,000
  const size_t OFF_UPDV = 2953216;                  // NB*8*3 f32 = 5,760,000
  const size_t OFF_HB   = 8713216;                  // 160000*128 bf16 = 40,960,000
  const size_t OFF_MSG  = 49673216;                 // NB*8*128 bf16 = 122,880,000

  int*   degI = (int*)(ws + OFF_DEG);
  bf16*  W1p  = (bf16*)(ws + OFF_W1);
  bf16*  W2p  = (bf16*)(ws + OFF_W2);
  bf16*  Wn1p = (bf16*)(ws + OFF_WN1);
  bf16*  Wn2p = (bf16*)(ws + OFF_WN2);
  bf16*  Wc1p = (bf16*)(ws + OFF_WC1);
  int*   adj2 = (int*)(ws + OFF_ADJ2);
  float* updv = (float*)(ws + OFF_UPDV);
  bf16*  hb   = (bf16*)(ws + OFF_HB);
  bf16*  msgB = (bf16*)(ws + OFF_MSG);

  (void)hipMemsetAsync(degI, 0, NA * sizeof(int), stream);

  cast_h<<<NBATCH * NA * H / 1024, 256, 0, stream>>>(h, hb);
  pack_all<<<448, 256, 0, stream>>>(Wm1, Wm2, Wn1, Wn2, Wc1,
                                    W1p, W2p, Wn1p, Wn2p, Wc1p);
  build_adj2<<<(NB + 255) / 256, 256, 0, stream>>>(bonds, degI, adj2);

  msg_kernel<<<NB * NBATCH / 64, 256, 0, stream>>>(
      hb, x, bonds, W1p, bm1, W2p, bm2, Wm1 + 256 * H, Wc1p, bc1, Wc2,
      msgB, updv);
  node_kernel<<<NBATCH * NA / 32, 256, 0, stream>>>(
      h, hb, msgB, updv, degI, adj2, Wn1p, bn1, Wn2p, bn2, x,
      hout, xout);
}